// Round 14
// baseline (366.973 us; speedup 1.0000x reference)
//
#include <hip/hip_runtime.h>
#include <math.h>

// ---------------------------------------------------------------------------
// Transformer encoder block, MI355X gfx950.  Round 14: full-cacheline staging.
//   - gemm8p LDS -> [buf][row][64] full K=64 tiles (A and B).  Staging reads
//     128B-contiguous rows (full cachelines; was 64B half-rows -> 2x FETCH
//     amplification, confirmed by counters).  ks-half select via addr^(ks*64);
//     swizzle off ^= (lr&7)<<4 (2-way banks per 16-lane phase).
//   - stage slots: A-d1@p0, B-d0@p2, A-d0@p4, B-d1@p6; vmcnt(4) at p3/p7.
//   - everything else verbatim from round 13 (passing, 362.8 us).
// ---------------------------------------------------------------------------

typedef unsigned short u16;
typedef unsigned int u32;
typedef __attribute__((ext_vector_type(8))) short bf16x8;   // 8 bf16 = 4 VGPRs
typedef __attribute__((ext_vector_type(4))) float f32x4;

#define T_TOK 8192      // 4 * 2048 tokens
#define DM    1024      // model dim
#define SEQ   2048
#define PST   88        // attn ldsP row stride (u16)
#define TST   136       // V-transpose LDS row stride (u16)

__device__ __forceinline__ u16 f2bf(float f) {
  union { float f; unsigned int u; } c; c.f = f;
  unsigned int u = c.u + 0x7fffu + ((c.u >> 16) & 1u);   // RNE
  return (u16)(u >> 16);
}

__device__ __forceinline__ u32 pk2(float a, float b) {
  return (u32)f2bf(a) | ((u32)f2bf(b) << 16);
}

__device__ __forceinline__ float bf2f(short s) {
  union { float f; unsigned int u; } c; c.u = ((u32)(u16)s) << 16;
  return c.f;
}

__device__ __forceinline__ void gload16(const void* gp, void* lp) {
  __builtin_amdgcn_global_load_lds(
      (const __attribute__((address_space(1))) void*)gp,
      (__attribute__((address_space(3))) void*)lp, 16, 0, 0);
}

__device__ __forceinline__ float gelu_tanh(float v) {
  float u = 0.7978845608f * (v + 0.044715f * v * v * v);
  return v / (1.0f + __expf(-2.0f * u));
}

// ---------------------------------------------------------------------------
// prep_kernel: blocks [0,8192) = LN1 rows; [8192,10240) = weight casts;
//              [10240,10252) = qkv bias concat.
// ---------------------------------------------------------------------------
__global__ __launch_bounds__(256) void prep_kernel(
    const float* __restrict__ x, const float* __restrict__ g,
    const float* __restrict__ b, u16* __restrict__ xnB,
    const float* __restrict__ Wq, const float* __restrict__ Wk,
    const float* __restrict__ Wv, const float* __restrict__ Wo,
    const float* __restrict__ W1, const float* __restrict__ W2,
    u16* __restrict__ WqkvB, u16* __restrict__ WoB,
    u16* __restrict__ W1B, u16* __restrict__ W2B,
    const float* __restrict__ bq, const float* __restrict__ bk,
    const float* __restrict__ bv, float* __restrict__ bqkv) {
  __shared__ float red[4];
  const int bid = blockIdx.x, tid = threadIdx.x;
  if (bid < 8192) {
    // ---- LayerNorm row (ddof=1, eps after sqrt) ----
    const int l = tid & 63, w = tid >> 6;
    const size_t row = bid;
    float4 v = reinterpret_cast<const float4*>(x + row * DM)[tid];
    float s = v.x + v.y + v.z + v.w;
#pragma unroll
    for (int off = 1; off < 64; off <<= 1) s += __shfl_xor(s, off, 64);
    if (l == 0) red[w] = s;
    __syncthreads();
    float mu = (red[0] + red[1] + red[2] + red[3]) * (1.0f / 1024.0f);
    float dx = v.x - mu, dy = v.y - mu, dz = v.z - mu, dw = v.w - mu;
    float ss = dx * dx + dy * dy + dz * dz + dw * dw;
#pragma unroll
    for (int off = 1; off < 64; off <<= 1) ss += __shfl_xor(ss, off, 64);
    __syncthreads();
    if (l == 0) red[w] = ss;
    __syncthreads();
    float var = (red[0] + red[1] + red[2] + red[3]) * (1.0f / 1023.0f);
    float inv = 1.0f / (sqrtf(var) + 1e-8f);
    const int c = tid * 4;
    u16* o = xnB + row * DM + c;
    o[0] = f2bf(dx * inv * g[c + 0] + b[c + 0]);
    o[1] = f2bf(dy * inv * g[c + 1] + b[c + 1]);
    o[2] = f2bf(dz * inv * g[c + 2] + b[c + 2]);
    o[3] = f2bf(dw * inv * g[c + 3] + b[c + 3]);
  } else if (bid < 10240) {
    // ---- weight casts: virtual 2048-block grid-stride over 3.14M float4 ----
    for (int i = (bid - 8192) * 256 + tid; i < 3145728; i += 2048 * 256) {
      const float* s; u16* d; int j;
      if (i < 262144)       { s = Wq; d = WqkvB;           j = i; }
      else if (i < 524288)  { s = Wk; d = WqkvB + 1048576; j = i - 262144; }
      else if (i < 786432)  { s = Wv; d = WqkvB + 2097152; j = i - 524288; }
      else if (i < 1048576) { s = Wo; d = WoB;             j = i - 786432; }
      else if (i < 2097152) { s = W1; d = W1B;             j = i - 1048576; }
      else                  { s = W2; d = W2B;             j = i - 2097152; }
      float4 v = reinterpret_cast<const float4*>(s)[j];
      ushort4 o = { f2bf(v.x), f2bf(v.y), f2bf(v.z), f2bf(v.w) };
      reinterpret_cast<ushort4*>(d)[j] = o;
    }
  } else {
    // ---- qkv bias concat ----
    int i = (bid - 10240) * 256 + tid;           // 0..3071
    float val = (i < 1024) ? bq[i] : (i < 2048) ? bk[i - 1024] : bv[i - 2048];
    bqkv[i] = val;
  }
}

// ---------------------------------------------------------------------------
// LayerNorm (standalone, used for LN2)
// ---------------------------------------------------------------------------
__global__ __launch_bounds__(256) void ln_kernel(const float* __restrict__ x,
    const float* __restrict__ g, const float* __restrict__ b, u16* __restrict__ out) {
  __shared__ float red[4];
  const int tid = threadIdx.x, l = tid & 63, w = tid >> 6;
  const size_t row = blockIdx.x;
  float4 v = reinterpret_cast<const float4*>(x + row * DM)[tid];
  float s = v.x + v.y + v.z + v.w;
#pragma unroll
  for (int off = 1; off < 64; off <<= 1) s += __shfl_xor(s, off, 64);
  if (l == 0) red[w] = s;
  __syncthreads();
  float mu = (red[0] + red[1] + red[2] + red[3]) * (1.0f / 1024.0f);
  float dx = v.x - mu, dy = v.y - mu, dz = v.z - mu, dw = v.w - mu;
  float ss = dx * dx + dy * dy + dz * dz + dw * dw;
#pragma unroll
  for (int off = 1; off < 64; off <<= 1) ss += __shfl_xor(ss, off, 64);
  __syncthreads();                       // guard red[] reuse
  if (l == 0) red[w] = ss;
  __syncthreads();
  float var = (red[0] + red[1] + red[2] + red[3]) * (1.0f / 1023.0f);
  float inv = 1.0f / (sqrtf(var) + 1e-8f);
  const int c = tid * 4;
  u16* o = out + row * DM + c;
  o[0] = f2bf(dx * inv * g[c + 0] + b[c + 0]);
  o[1] = f2bf(dy * inv * g[c + 1] + b[c + 1]);
  o[2] = f2bf(dz * inv * g[c + 2] + b[c + 2]);
  o[3] = f2bf(dw * inv * g[c + 3] + b[c + 3]);
}

// ---------------------------------------------------------------------------
// gemm8p<EPI, BM>: C[M,N] = A[M,K] @ Bw[N,K]^T + bias (+res) (+gelu)
// 8-phase schedule, BK=64, 2 K-tiles per loop iteration.
// LDS: A [2][BM][64], B [2][256][64] (full K-tiles; 128B rows).  Staging
// reads full cachelines; ks-half selected on ds_read via addr^(ks*64).
// EPI 0: QKV (Q,K -> Cout [T][2048]; V tile -> in-LDS transpose -> aux VT).
// EPI 1: f32 out (bias+res).  EPI 2: bf16 out (bias+gelu)
// ---------------------------------------------------------------------------
template <int EPI, int BM>
__global__ __launch_bounds__(512) void gemm8p(const u16* __restrict__ A,
    const u16* __restrict__ Bw, const float* __restrict__ bias,
    const float* res, void* Cout, void* aux, int M, int N, int K, int gx) {
  constexpr int MI  = BM / 32;                 // acc rows (8 or 4)
  constexpr int AMI = MI / 2;                  // A frags per phase (4 or 2)
  constexpr int LA4 = BM / 64;                 // A stage passes (4 or 2)
  __shared__ __align__(16) u16 shm[2 * BM * 64 + 2 * 256 * 64];
  const int tid = threadIdx.x;
  const int l = tid & 63;
  const int w = tid >> 6;
  const int wm = w >> 2, wn = w & 3;
  const int lr = l & 15, lg = l >> 4;

  // ---- XCD supertile remap (T1) ----
  const int nb = gridDim.x;
  const int q = nb >> 3, r = nb & 7;
  const int xcd = blockIdx.x & 7, jj = blockIdx.x >> 3;
  const int lid = (xcd < r ? xcd * (q + 1) : r * (q + 1) + (xcd - r) * q) + jj;
  const int stid = lid >> 5, pos = lid & 31;
  const int nstx = gx >> 2;
  const int stx = stid % nstx, sty = stid / nstx;
  const int bx = stx * 4 + (pos & 3), by = sty * 8 + (pos >> 2);
  const int m0 = by * BM, n0 = bx * 256;

  // ---- staging source (pre-swizzled, 128B rows): thread covers 16B ----
  const int trow  = tid >> 3;                                // 0..63 (+64/pass)
  const int scolE = ((((tid & 7) * 16) ^ ((trow & 7) << 4)) >> 1);
  const u16* aS0 = A  + (size_t)(m0 + trow) * K + scolE;
  const u16* bS0 = Bw + (size_t)(n0 + trow) * K + scolE;

  // ---- ds_read bases (swizzled; ks selected by ^ (ks*64) on byte addr) ----
  const int sx = (lr & 7) << 4;
  const int aBase = (wm * (BM / 2) + lr) * 128 + ((lg * 16) ^ sx);  // bytes
  const int bBase = (wn * 64 + lr) * 128 + ((lg * 16) ^ sx);

  f32x4 acc[MI][4];
#pragma unroll
  for (int i = 0; i < MI; ++i)
#pragma unroll
    for (int j = 0; j < 4; ++j) acc[i][j] = f32x4{0.f, 0.f, 0.f, 0.f};
  bf16x8 bv[2][4];

  const int NT = K >> 6;               // K-tiles of 64
  const int NI = NT >> 1;              // loop iterations (2 tiles each)

  auto stA = [&](int d, int tile) {    // full A tile: LA4 passes x 16B/thread
    u16* dst = shm + d * (BM * 64) + tid * 8;
    const u16* src = aS0 + tile * 64;
#pragma unroll
    for (int p = 0; p < LA4; ++p)
      gload16(src + (size_t)p * 64 * K, dst + p * 4096);
  };
  auto stB = [&](int d, int tile) {    // full B tile: 4 passes
    u16* dst = shm + 2 * BM * 64 + d * (256 * 64) + tid * 8;
    const u16* src = bS0 + tile * 64;
#pragma unroll
    for (int p = 0; p < 4; ++p)
      gload16(src + (size_t)p * 64 * K, dst + p * 4096);
  };

  // ---- prologue: d0 <- tile0 (A+B), d1 <- tile1 (B only; A staged at p0) ----
  stB(0, 0); stA(0, 0); stB(1, 1);
  asm volatile("s_waitcnt vmcnt(4)" ::: "memory");   // tile0 landed, B-d1 fly
  __builtin_amdgcn_sched_barrier(0);
  __builtin_amdgcn_s_barrier();

#define PHASE(DBUF, KS, MH, READB, STAGE, ENDV)                               \
  {                                                                           \
    const char* abuf = (const char*)(shm + (DBUF) * (BM * 64));               \
    const char* bbuf = (const char*)(shm + 2 * BM * 64 + (DBUF) * (256 * 64));\
    bf16x8 av[AMI];                                                           \
    _Pragma("unroll")                                                         \
    for (int i = 0; i < AMI; ++i)                                             \
      av[i] = *(const bf16x8*)(abuf + (aBase ^ ((KS) * 64)) +                 \
                               ((MH) * AMI + i) * 2048);                      \
    if (READB) {                                                              \
      _Pragma("unroll")                                                       \
      for (int ni = 0; ni < 4; ++ni)                                          \
        bv[KS][ni] = *(const bf16x8*)(bbuf + (bBase ^ ((KS) * 64)) +          \
                                      ni * 2048);                             \
    }                                                                         \
    STAGE;                                                                    \
    __builtin_amdgcn_s_barrier();                                             \
    asm volatile("s_waitcnt lgkmcnt(0)" ::: "memory");                        \
    __builtin_amdgcn_sched_barrier(0);                                        \
    __builtin_amdgcn_s_setprio(1);                                            \
    _Pragma("unroll")                                                         \
    for (int i = 0; i < AMI; ++i)                                             \
      _Pragma("unroll")                                                       \
      for (int ni = 0; ni < 4; ++ni)                                          \
        acc[(MH) * AMI + i][ni] = __builtin_amdgcn_mfma_f32_16x16x32_bf16(    \
            av[i], bv[KS][ni], acc[(MH) * AMI + i][ni], 0, 0, 0);             \
    __builtin_amdgcn_s_setprio(0);                                            \
    ENDV;                                                                     \
    __builtin_amdgcn_s_barrier();                                             \
  }

#define ENDV_CNT                                                              \
  {                                                                           \
    if (t + 1 < NI) {                                                         \
      asm volatile("s_waitcnt vmcnt(4)" ::: "memory");                        \
    } else {                                                                  \
      asm volatile("s_waitcnt vmcnt(0)" ::: "memory");                        \
    }                                                                         \
    __builtin_amdgcn_sched_barrier(0);                                        \
  }

  for (int t = 0; t < NI; ++t) {
    const int t2 = 2 * t;
    const bool s0 = (t2 + 2 < NT);     // stage tile 2t+2 (d0)
    const bool s1 = (t2 + 3 < NT);     // stage tile 2t+3 (d1)
    // p0..p3: compute tile 2t (d0); p4..p7: tile 2t+1 (d1)
    PHASE(0, 0, 0, 1, { stA(1, t2 + 1); }, {});                // p0
    PHASE(0, 1, 0, 1, {}, {});                                 // p1
    PHASE(0, 0, 1, 0, { if (s0) stB(0, t2 + 2); }, {});        // p2
    PHASE(0, 1, 1, 0, {}, ENDV_CNT);                           // p3
    PHASE(1, 0, 0, 1, { if (s0) stA(0, t2 + 2); }, {});        // p4
    PHASE(1, 1, 0, 1, {}, {});                                 // p5
    PHASE(1, 0, 1, 0, { if (s1) stB(1, t2 + 3); }, {});        // p6
    PHASE(1, 1, 1, 0, {}, ENDV_CNT);                           // p7
  }
#undef PHASE
#undef ENDV_CNT

  // ---- epilogue ----
  float bs[4];
#pragma unroll
  for (int ni = 0; ni < 4; ++ni) bs[ni] = bias[n0 + wn * 64 + ni * 16 + lr];

  if constexpr (EPI == 0) {
    if (n0 >= 2048) {
      // ---- V tile: in-LDS transpose, coalesced VT write ----
      u16* ldsT = shm;                          // 256*TST u16 fits
#pragma unroll
      for (int mi = 0; mi < MI; ++mi)
#pragma unroll
        for (int ni = 0; ni < 4; ++ni) {
          const int c = wn * 64 + ni * 16 + lr;
          const int r0 = wm * (BM / 2) + mi * 16 + lg * 4;
          ushort4 pk = { f2bf(acc[mi][ni][0] + bs[ni]),
                         f2bf(acc[mi][ni][1] + bs[ni]),
                         f2bf(acc[mi][ni][2] + bs[ni]),
                         f2bf(acc[mi][ni][3] + bs[ni]) };
          *(ushort4*)&ldsT[c * TST + r0] = pk;
        }
      __syncthreads();
      const int b0 = m0 >> 11, s0b = m0 & 2047;
      const int cc = tid >> 1, hf = tid & 1;
      const int hd = (n0 - 2048) + cc, hh = hd >> 6, dd = hd & 63;
      u16* dst = (u16*)aux +
                 (((size_t)(b0 * 16 + hh) * 64 + dd) << 11) + s0b + hf * 64;
      const u16* srcT = &ldsT[cc * TST + hf * 64];
#pragma unroll
      for (int i2 = 0; i2 < 8; ++i2)
        *(bf16x8*)(dst + i2 * 8) = *(const bf16x8*)(srcT + i2 * 8);
      return;
    }
  }

#pragma unroll
  for (int mi = 0; mi < MI; ++mi) {
#pragma unroll
    for (int j = 0; j < 4; ++j) {
      const int rr = m0 + wm * (BM / 2) + mi * 16 + lg * 4 + j;
#pragma unroll
      for (int ni = 0; ni < 4; ++ni) {
        const int c = n0 + wn * 64 + ni * 16 + lr;
        float v = acc[mi][ni][j] + bs[ni];
        if constexpr (EPI == 0) {
          ((u16*)Cout)[(size_t)rr * 2048 + c] = f2bf(v);   // Q,K -> [T][2048]
        } else if constexpr (EPI == 1) {
          const size_t idx = (size_t)rr * N + c;
          ((float*)Cout)[idx] = v + res[idx];
        } else {
          const size_t idx = (size_t)rr * N + c;
          ((u16*)Cout)[idx] = f2bf(gelu_tanh(v));
        }
      }
    }
  }
}

// ---------------------------------------------------------------------------
// Flash attention (causal), swapped-QK + transposed-PV; 3-ring staged K/V.
// (unchanged from round 13)
// ---------------------------------------------------------------------------
__global__ __launch_bounds__(512) void attn_kernel(const u16* __restrict__ qk,
    const u16* __restrict__ vt, u16* __restrict__ obuf) {
  __shared__ __align__(16) u16 ldsK[3][64 * 64];
  __shared__ __align__(16) u16 ldsV[3][64 * 64];
  __shared__ __align__(16) u16 ldsP[8][2][16 * PST];
  const int tid = threadIdx.x, l = tid & 63, w = tid >> 6;
  const int lr = l & 15, lg = l >> 4;
  const int lid = (blockIdx.x & 7) * 32 + (blockIdx.x >> 3);   // 256 blocks
  const int bh = lid >> 2, bx = lid & 3;
  const int b = bh >> 4, h = bh & 15;
  const u16* qbase = qk + (size_t)b * SEQ * 2048 + h * 64;
  const u16* kbase = qk + (size_t)b * SEQ * 2048 + 1024 + h * 64;
  const u16* vbase = vt + (size_t)bh * 64 * SEQ;

  const int srow = tid >> 3;                     // 0..63
  const int scb  = ((tid & 7) * 16) ^ ((srow & 7) << 4);   // swizzled col bytes
  const int sel  = scb >> 1;                     // element offset in 64-col row

  auto stageKV = [&](int t) {
    const int bi = t % 3;
    gload16(kbase + (size_t)(t * 64 + srow) * 2048 + sel, &ldsK[bi][tid * 8]);
    gload16(vbase + (size_t)srow * SEQ + t * 64 + sel,    &ldsV[bi][tid * 8]);
  };

#pragma unroll
  for (int half = 0; half < 2; ++half) {
    const int qt = half ? (7 - bx) : bx;
    const int q0 = qt * 256 + w * 32;            // wave's first q row
    bf16x8 qf[2][2];
#pragma unroll
    for (int mi = 0; mi < 2; ++mi)
#pragma unroll
      for (int ks = 0; ks < 2; ++ks) {
        bf16x8 raw = *(const bf16x8*)(qbase +
            (size_t)(q0 + mi * 16 + lr) * 2048 + ks * 32 + lg * 8);
        bf16x8 sc8;
#pragma unroll
        for (int i = 0; i < 8; ++i) sc8[i] = (short)f2bf(bf2f(raw[i]) * 0.125f);
        qf[mi][ks] = sc8;
      }

    f32x4 o[2][4];
#pragma unroll
    for (int mi = 0; mi < 2; ++mi)
#pragma unroll
      for (int nd = 0; nd < 4; ++nd) o[mi][nd] = f32x4{0.f, 0.f, 0.f, 0.f};
    float m_[2] = {-1e30f, -1e30f}, ls[2] = {0.f, 0.f};

    const int nt = 4 * qt + 4;
    const int qmaxw = q0 + 31;

    stageKV(0);                                  // prologue

    for (int kt = 0; kt < nt; ++kt) {
      if (kt + 1 < nt) {
        stageKV(kt + 1);
        asm volatile("s_waitcnt vmcnt(2)" ::: "memory");   // kt landed
      } else {
        asm volatile("s_waitcnt vmcnt(0)" ::: "memory");
      }
      __builtin_amdgcn_s_barrier();              // publish kt (all waves)
      __builtin_amdgcn_sched_barrier(0);
      const u16* bK = &ldsK[kt % 3][0];
      const u16* bV = &ldsV[kt % 3][0];

      if (kt * 64 <= qmaxw) {          // wave has live rows in this k-tile
        // ---- S^T = K . Q^T  (col = q = lr, row = key) ----
        f32x4 sc[2][4];
#pragma unroll
        for (int mi = 0; mi < 2; ++mi)
#pragma unroll
          for (int ni = 0; ni < 4; ++ni) sc[mi][ni] = f32x4{0.f, 0.f, 0.f, 0.f};
#pragma unroll
        for (int ks = 0; ks < 2; ++ks)
#pragma unroll
          for (int ni = 0; ni < 4; ++ni) {
            const int r2 = ni * 16 + lr;
            const int cb = (r2 << 7) + ((ks * 64 + lg * 16) ^ ((r2 & 7) << 4));
            bf16x8 kf = *(const bf16x8*)&bK[cb >> 1];
            sc[0][ni] = __builtin_amdgcn_mfma_f32_16x16x32_bf16(kf, qf[0][ks], sc[0][ni], 0, 0, 0);
            sc[1][ni] = __builtin_amdgcn_mfma_f32_16x16x32_bf16(kf, qf[1][ks], sc[1][ni], 0, 0, 0);
          }

        // ---- causal mask ----
        if (kt * 64 + 63 > q0) {
#pragma unroll
          for (int mi = 0; mi < 2; ++mi) {
            const int qa = q0 + mi * 16 + lr;
#pragma unroll
            for (int ni = 0; ni < 4; ++ni)
#pragma unroll
              for (int j = 0; j < 4; ++j) {
                const int ka = kt * 64 + ni * 16 + lg * 4 + j;
                if (ka > qa) sc[mi][ni][j] = -1e30f;
              }
          }
        }

        // ---- online softmax (lane-local row q = lr; T13 defer-max) ----
#pragma unroll
        for (int mi = 0; mi < 2; ++mi) {
          float mx = sc[mi][0][0];
#pragma unroll
          for (int ni = 0; ni < 4; ++ni)
#pragma unroll
            for (int j = 0; j < 4; ++j) mx = fmaxf(mx, sc[mi][ni][j]);
          mx = fmaxf(mx, __shfl_xor(mx, 16, 64));
          mx = fmaxf(mx, __shfl_xor(mx, 32, 64));
          if (!__all(mx <= m_[mi] + 8.0f)) {     // rescale only when needed
            const float newm = fmaxf(m_[mi], mx);
            const float alpha = __expf(m_[mi] - newm);
            m_[mi] = newm;
            ls[mi] *= alpha;
#pragma unroll
            for (int nd = 0; nd < 4; ++nd) {
              o[mi][nd][0] *= alpha; o[mi][nd][1] *= alpha;
              o[mi][nd][2] *= alpha; o[mi][nd][3] *= alpha;
            }
          }
          float ps = 0.f;
#pragma unroll
          for (int ni = 0; ni < 4; ++ni) {
            float p0 = __expf(sc[mi][ni][0] - m_[mi]);
            float p1 = __expf(sc[mi][ni][1] - m_[mi]);
            float p2 = __expf(sc[mi][ni][2] - m_[mi]);
            float p3 = __expf(sc[mi][ni][3] - m_[mi]);
            ps += (p0 + p1) + (p2 + p3);
            u32 w0 = pk2(p0, p1), w1 = pk2(p2, p3);
            *(uint2*)&ldsP[w][mi][lr * PST + ni * 16 + lg * 4] = make_uint2(w0, w1);
          }
          ps += __shfl_xor(ps, 16, 64);          // row total (across lg)
          ps += __shfl_xor(ps, 32, 64);
          ls[mi] += ps;
        }

        // ---- O^T += V^T . P  (row = d, col = q = lr) ----
#pragma unroll
        for (int ks = 0; ks < 2; ++ks) {
          bf16x8 pf0 = *(const bf16x8*)&ldsP[w][0][lr * PST + ks * 32 + lg * 8];
          bf16x8 pf1 = *(const bf16x8*)&ldsP[w][1][lr * PST + ks * 32 + lg * 8];
#pragma unroll
          for (int nd = 0; nd < 4; ++nd) {
            const int r2 = nd * 16 + lr;
            const int cb = (r2 << 7) + ((ks * 64 + lg * 16) ^ ((r2 & 7) << 4));
            bf16x8 vf = *(const bf16x8*)&bV[cb >> 1];
            o[0][nd] = __builtin_amdgcn_mfma_f32_16x16x32_bf16(vf, pf0, o[0][nd], 0, 0, 0);
            o[1][nd] = __builtin_amdgcn_mfma_f32_16x16x32_bf16(vf, pf1, o[1][nd], 0, 0, 0);
          }
        }
      }
    }
    __builtin_amdgcn_s_barrier();     // protect bufs before next half restages

    // ---- epilogue: O^T / l ; q = lr (lane-local), d = nd*16 + lg*4 + j ----
#pragma unroll
    for (int mi = 0; mi < 2; ++mi) {
      const float inv = 1.0f / ls[mi];
      const int qrow = q0 + mi * 16 + lr;
      u16* op = obuf + (size_t)(b * SEQ + qrow) * DM + h * 64 + lg * 4;
#pragma unroll
      for (int nd = 0; nd < 4; ++nd) {
        ushort4 pk = { f2bf(o[mi][nd][0] * inv), f2bf(o[mi][nd][1] * inv),
                       f2bf(o[mi][nd][2] * inv), f2bf(o[mi][nd][3] * inv) };
        *(ushort4*)(op + nd * 16) = pk;
      }
    }
  }
}

// ---------------------------------------------------------------------------
extern "C" void kernel_launch(void* const* d_in, const int* in_sizes, int n_in,
                              void* d_out, int out_size, void* d_ws, size_t ws_size,
                              hipStream_t stream) {
  const float* x   = (const float*)d_in[0];
  const float* Wq  = (const float*)d_in[1];
  const float* bq  = (const float*)d_in[2];
  const float* Wk  = (const float*)d_in[3];
  const float* bk  = (const float*)d_in[4];
  const float* Wv  = (const float*)d_in[5];
  const float* bv  = (const float*)d_in[6];
  const float* Wo  = (const float*)d_in[7];
  const float* bo  = (const float*)d_in[8];
  const float* g1  = (const float*)d_in[9];
  const float* be1 = (const float*)d_in[10];
  const float* g2  = (const float*)d_in[11];
  const float* be2 = (const float*)d_in[12];
  const float* W1  = (const float*)d_in[13];
  const float* bf1 = (const float*)d_in[14];
  const float* W2  = (const float*)d_in[15];
  const float* bf2 = (const float*)d_in[16];
  float* out = (float*)d_out;   // also hosts x1 (post-attn residual)

  char* ws = (char*)d_ws;
  size_t off = 0;
  auto alloc = [&](size_t bytes) {
    char* p = ws + off;
    off += (bytes + 255) & ~(size_t)255;
    return p;
  };
  u16* xnB = (u16*)alloc((size_t)T_TOK * DM * 2);     // 16 MB (xn, later xn2)
  // Region D (64 MB): MHA = qkB(32) | VTg(16) | oB(16); FFN = H(64)
  u16* D    = (u16*)alloc((size_t)T_TOK * 4096 * 2);  // 64 MB
  u16* qkB  = D;                                      // [T][2048]
  u16* VTg  = D + (size_t)T_TOK * 2048;               // [B*H][64][2048]
  u16* oB   = D + (size_t)T_TOK * 3072;               // [T][1024] attn out
  u16* HB   = D;                                      // [T][4096] (FFN phase)
  u16*   WqkvB = (u16*)alloc((size_t)3072 * 1024 * 2);
  u16*   WoB   = (u16*)alloc((size_t)1024 * 1024 * 2);
  u16*   W1B   = (u16*)alloc((size_t)4096 * 1024 * 2);
  u16*   W2B   = (u16*)alloc((size_t)1024 * 4096 * 2);
  float* bqkv  = (float*)alloc(3072 * 4);

  // fused prep: LN1 + weight casts + bias concat (one launch)
  prep_kernel<<<10252, 256, 0, stream>>>(x, g1, be1, xnB,
                                         Wq, Wk, Wv, Wo, W1, W2,
                                         WqkvB, WoB, W1B, W2B,
                                         bq, bk, bv, bqkv);

  // MHA sublayer (QKV writes Q,K -> qkB and transposed V -> VTg directly)
  gemm8p<0, 128><<<768, 512, 0, stream>>>(xnB, WqkvB, bqkv, nullptr,
                                          qkB, VTg, T_TOK, 3072, 1024, 12);
  attn_kernel<<<256, 512, 0, stream>>>(qkB, VTg, oB);
  gemm8p<1, 128><<<256, 512, 0, stream>>>(oB, WoB, bo, x,
                                          out, nullptr, T_TOK, 1024, 1024, 4);

  // FFN sublayer
  ln_kernel<<<T_TOK, 256, 0, stream>>>(out, g2, be2, xnB);
  gemm8p<2, 256><<<512, 512, 0, stream>>>(xnB, W1B, bf1, nullptr,
                                          HB, nullptr, T_TOK, 4096, 1024, 16);
  gemm8p<1, 128><<<256, 512, 0, stream>>>(HB, W2B, bf2, out,
                                          out, nullptr, T_TOK, 1024, 4096, 4);
}

// Round 15
// 363.931 us; speedup vs baseline: 1.0084x; 1.0084x over previous
//
#include <hip/hip_runtime.h>
#include <math.h>

// ---------------------------------------------------------------------------
// Transformer encoder block, MI355X gfx950.  Round 15: 2 blocks/CU x 8-phase.
//   - gemm8p: 128x128 tile, 256 thr (4 waves 2Mx2N), 64 KB LDS -> 2 resident
//     blocks/CU.  Schedule = round-13 8-phase verbatim (half-tile staging,
//     K=32 halves, same swizzle); vmcnt(6) ledger re-derived for 2-load units.
//     Mechanism: independent blocks' phases interleave (m114) -> one block's
//     lgkm-drain/barrier overlaps the other's MFMA.
//   - round-14 full-line staging reverted (refuted: FETCH unchanged).
//   - prep / LN / attn verbatim from round 13 (passing).
// ---------------------------------------------------------------------------

typedef unsigned short u16;
typedef unsigned int u32;
typedef __attribute__((ext_vector_type(8))) short bf16x8;   // 8 bf16 = 4 VGPRs
typedef __attribute__((ext_vector_type(4))) float f32x4;

#define T_TOK 8192      // 4 * 2048 tokens
#define DM    1024      // model dim
#define SEQ   2048
#define PST   88        // attn ldsP row stride (u16)
#define TST   136       // V-transpose LDS row stride (u16)

__device__ __forceinline__ u16 f2bf(float f) {
  union { float f; unsigned int u; } c; c.f = f;
  unsigned int u = c.u + 0x7fffu + ((c.u >> 16) & 1u);   // RNE
  return (u16)(u >> 16);
}

__device__ __forceinline__ u32 pk2(float a, float b) {
  return (u32)f2bf(a) | ((u32)f2bf(b) << 16);
}

__device__ __forceinline__ float bf2f(short s) {
  union { float f; unsigned int u; } c; c.u = ((u32)(u16)s) << 16;
  return c.f;
}

__device__ __forceinline__ void gload16(const void* gp, void* lp) {
  __builtin_amdgcn_global_load_lds(
      (const __attribute__((address_space(1))) void*)gp,
      (__attribute__((address_space(3))) void*)lp, 16, 0, 0);
}

__device__ __forceinline__ float gelu_tanh(float v) {
  float u = 0.7978845608f * (v + 0.044715f * v * v * v);
  return v / (1.0f + __expf(-2.0f * u));
}

// ---------------------------------------------------------------------------
// prep_kernel: blocks [0,8192) = LN1 rows; [8192,10240) = weight casts;
//              [10240,10252) = qkv bias concat.
// ---------------------------------------------------------------------------
__global__ __launch_bounds__(256) void prep_kernel(
    const float* __restrict__ x, const float* __restrict__ g,
    const float* __restrict__ b, u16* __restrict__ xnB,
    const float* __restrict__ Wq, const float* __restrict__ Wk,
    const float* __restrict__ Wv, const float* __restrict__ Wo,
    const float* __restrict__ W1, const float* __restrict__ W2,
    u16* __restrict__ WqkvB, u16* __restrict__ WoB,
    u16* __restrict__ W1B, u16* __restrict__ W2B,
    const float* __restrict__ bq, const float* __restrict__ bk,
    const float* __restrict__ bv, float* __restrict__ bqkv) {
  __shared__ float red[4];
  const int bid = blockIdx.x, tid = threadIdx.x;
  if (bid < 8192) {
    const int l = tid & 63, w = tid >> 6;
    const size_t row = bid;
    float4 v = reinterpret_cast<const float4*>(x + row * DM)[tid];
    float s = v.x + v.y + v.z + v.w;
#pragma unroll
    for (int off = 1; off < 64; off <<= 1) s += __shfl_xor(s, off, 64);
    if (l == 0) red[w] = s;
    __syncthreads();
    float mu = (red[0] + red[1] + red[2] + red[3]) * (1.0f / 1024.0f);
    float dx = v.x - mu, dy = v.y - mu, dz = v.z - mu, dw = v.w - mu;
    float ss = dx * dx + dy * dy + dz * dz + dw * dw;
#pragma unroll
    for (int off = 1; off < 64; off <<= 1) ss += __shfl_xor(ss, off, 64);
    __syncthreads();
    if (l == 0) red[w] = ss;
    __syncthreads();
    float var = (red[0] + red[1] + red[2] + red[3]) * (1.0f / 1023.0f);
    float inv = 1.0f / (sqrtf(var) + 1e-8f);
    const int c = tid * 4;
    u16* o = xnB + row * DM + c;
    o[0] = f2bf(dx * inv * g[c + 0] + b[c + 0]);
    o[1] = f2bf(dy * inv * g[c + 1] + b[c + 1]);
    o[2] = f2bf(dz * inv * g[c + 2] + b[c + 2]);
    o[3] = f2bf(dw * inv * g[c + 3] + b[c + 3]);
  } else if (bid < 10240) {
    for (int i = (bid - 8192) * 256 + tid; i < 3145728; i += 2048 * 256) {
      const float* s; u16* d; int j;
      if (i < 262144)       { s = Wq; d = WqkvB;           j = i; }
      else if (i < 524288)  { s = Wk; d = WqkvB + 1048576; j = i - 262144; }
      else if (i < 786432)  { s = Wv; d = WqkvB + 2097152; j = i - 524288; }
      else if (i < 1048576) { s = Wo; d = WoB;             j = i - 786432; }
      else if (i < 2097152) { s = W1; d = W1B;             j = i - 1048576; }
      else                  { s = W2; d = W2B;             j = i - 2097152; }
      float4 v = reinterpret_cast<const float4*>(s)[j];
      ushort4 o = { f2bf(v.x), f2bf(v.y), f2bf(v.z), f2bf(v.w) };
      reinterpret_cast<ushort4*>(d)[j] = o;
    }
  } else {
    int i = (bid - 10240) * 256 + tid;           // 0..3071
    float val = (i < 1024) ? bq[i] : (i < 2048) ? bk[i - 1024] : bv[i - 2048];
    bqkv[i] = val;
  }
}

// ---------------------------------------------------------------------------
// LayerNorm (standalone, used for LN2)
// ---------------------------------------------------------------------------
__global__ __launch_bounds__(256) void ln_kernel(const float* __restrict__ x,
    const float* __restrict__ g, const float* __restrict__ b, u16* __restrict__ out) {
  __shared__ float red[4];
  const int tid = threadIdx.x, l = tid & 63, w = tid >> 6;
  const size_t row = blockIdx.x;
  float4 v = reinterpret_cast<const float4*>(x + row * DM)[tid];
  float s = v.x + v.y + v.z + v.w;
#pragma unroll
  for (int off = 1; off < 64; off <<= 1) s += __shfl_xor(s, off, 64);
  if (l == 0) red[w] = s;
  __syncthreads();
  float mu = (red[0] + red[1] + red[2] + red[3]) * (1.0f / 1024.0f);
  float dx = v.x - mu, dy = v.y - mu, dz = v.z - mu, dw = v.w - mu;
  float ss = dx * dx + dy * dy + dz * dz + dw * dw;
#pragma unroll
  for (int off = 1; off < 64; off <<= 1) ss += __shfl_xor(ss, off, 64);
  __syncthreads();                       // guard red[] reuse
  if (l == 0) red[w] = ss;
  __syncthreads();
  float var = (red[0] + red[1] + red[2] + red[3]) * (1.0f / 1023.0f);
  float inv = 1.0f / (sqrtf(var) + 1e-8f);
  const int c = tid * 4;
  u16* o = out + row * DM + c;
  o[0] = f2bf(dx * inv * g[c + 0] + b[c + 0]);
  o[1] = f2bf(dy * inv * g[c + 1] + b[c + 1]);
  o[2] = f2bf(dz * inv * g[c + 2] + b[c + 2]);
  o[3] = f2bf(dw * inv * g[c + 3] + b[c + 3]);
}

// ---------------------------------------------------------------------------
// gemm8p<EPI>: C[M,N] = A[M,K](bf16) @ Bw[N,K](bf16)^T + bias (+res) (+gelu)
// 128x128 tile, 256 thr = 4 waves (2M x 2N), wave = 64x64 out.
// 8-phase / BK=64 / 2 K-tiles per iter; LDS = A[2][2][128*32] + B same = 64KB
// -> 2 blocks/CU.  Half-tile staging (2 loads/unit), vmcnt(6) at p3/p7.
// EPI 0: QKV (Q,K -> Cout [T][2048]; V tile -> in-LDS transpose -> aux VT).
// EPI 1: f32 out (bias+res).  EPI 2: bf16 out (bias+gelu)
// ---------------------------------------------------------------------------
template <int EPI>
__global__ __launch_bounds__(256) void gemm8p(const u16* __restrict__ A,
    const u16* __restrict__ Bw, const float* __restrict__ bias,
    const float* res, void* Cout, void* aux, int M, int N, int K, int gx) {
  __shared__ __align__(16) u16 shm[8 * 4096];   // A[4][4096] | B[4][4096]
  const int tid = threadIdx.x;
  const int l = tid & 63;
  const int w = tid >> 6;
  const int wm = w >> 1, wn = w & 1;
  const int lr = l & 15, lg = l >> 4;

  // ---- XCD supertile remap (T1): supertile = 4 N-blocks x 8 M-blocks ----
  const int nb = gridDim.x;
  const int q = nb >> 3, r = nb & 7;
  const int xcd = blockIdx.x & 7, jj = blockIdx.x >> 3;
  const int lid = (xcd < r ? xcd * (q + 1) : r * (q + 1) + (xcd - r) * q) + jj;
  const int stid = lid >> 5, pos = lid & 31;
  const int nstx = gx >> 2;
  const int stx = stid % nstx, sty = stid / nstx;
  const int bx = stx * 4 + (pos & 3), by = sty * 8 + (pos >> 2);
  const int m0 = by * 128, n0 = bx * 128;

  // ---- staging source (pre-swizzled): 256 thr cover 64 rows/pass ----
  const int srow  = tid >> 2;                               // 0..63
  const int scolE = ((((tid & 3) << 4) ^ ((srow & 6) << 3)) >> 1);
  const u16* aS0 = A  + (size_t)(m0 + srow) * K + scolE;
  const u16* aS1 = aS0 + (size_t)64 * K;                    // pass 1 (+64 rows)
  const u16* bS0 = Bw + (size_t)(n0 + srow) * K + scolE;
  const u16* bS1 = bS0 + (size_t)64 * K;

  // ---- ds_read bases (swizzled; XOR term constant per lane) ----
  const int sx = (lr & 6) << 3;
  const int aBase = (wm * 64 + lr) * 64 + ((lg * 16) ^ sx);   // bytes
  const int bBase = (wn * 64 + lr) * 64 + ((lg * 16) ^ sx);

  f32x4 acc[4][4];
#pragma unroll
  for (int i = 0; i < 4; ++i)
#pragma unroll
    for (int j = 0; j < 4; ++j) acc[i][j] = f32x4{0.f, 0.f, 0.f, 0.f};
  bf16x8 bv[2][4];

  const int NT = K >> 6;               // K-tiles of 64
  const int NI = NT >> 1;              // loop iterations (2 tiles each)

  auto stA = [&](int d, int ks, int tile) {
    u16* dst = shm + (d * 2 + ks) * 4096 + tid * 8;
    const int ko = tile * 64 + ks * 32;
    gload16(aS0 + ko, dst);
    gload16(aS1 + ko, dst + 2048);
  };
  auto stB = [&](int d, int ks, int tile) {
    u16* dst = shm + 4 * 4096 + (d * 2 + ks) * 4096 + tid * 8;
    const int ko = tile * 64 + ks * 32;
    gload16(bS0 + ko, dst);
    gload16(bS1 + ko, dst + 2048);
  };

  // ---- prologue: tile0 -> d0 (4 halves), tile1 -> d1 (B0,B1,A-ks0) ----
  stB(0, 0, 0); stB(0, 1, 0); stA(0, 0, 0); stA(0, 1, 0);
  stB(1, 0, 1); stB(1, 1, 1); stA(1, 0, 1);
  asm volatile("s_waitcnt vmcnt(6)" ::: "memory");
  __builtin_amdgcn_sched_barrier(0);
  __builtin_amdgcn_s_barrier();

#define PHASE(DBUF, KS, MH, READB, STAGE, ENDV)                               \
  {                                                                           \
    const char* abuf = (const char*)(shm + ((DBUF) * 2 + (KS)) * 4096);       \
    const char* bbuf = (const char*)(shm + (4 + (DBUF) * 2 + (KS)) * 4096);   \
    bf16x8 av[2];                                                             \
    _Pragma("unroll")                                                         \
    for (int i = 0; i < 2; ++i)                                               \
      av[i] = *(const bf16x8*)(abuf + aBase + ((MH) * 2 + i) * 1024);         \
    if (READB) {                                                              \
      _Pragma("unroll")                                                       \
      for (int ni = 0; ni < 4; ++ni)                                          \
        bv[KS][ni] = *(const bf16x8*)(bbuf + bBase + ni * 1024);              \
    }                                                                         \
    STAGE;                                                                    \
    __builtin_amdgcn_s_barrier();                                             \
    asm volatile("s_waitcnt lgkmcnt(0)" ::: "memory");                        \
    __builtin_amdgcn_sched_barrier(0);                                        \
    __builtin_amdgcn_s_setprio(1);                                            \
    _Pragma("unroll")                                                         \
    for (int i = 0; i < 2; ++i)                                               \
      _Pragma("unroll")                                                       \
      for (int ni = 0; ni < 4; ++ni)                                          \
        acc[(MH) * 2 + i][ni] = __builtin_amdgcn_mfma_f32_16x16x32_bf16(      \
            av[i], bv[KS][ni], acc[(MH) * 2 + i][ni], 0, 0, 0);               \
    __builtin_amdgcn_s_setprio(0);                                            \
    ENDV;                                                                     \
    __builtin_amdgcn_s_barrier();                                             \
  }

#define ENDV_CNT                                                              \
  {                                                                           \
    if (t + 1 < NI) {                                                         \
      asm volatile("s_waitcnt vmcnt(6)" ::: "memory");                        \
    } else {                                                                  \
      asm volatile("s_waitcnt vmcnt(0)" ::: "memory");                        \
    }                                                                         \
    __builtin_amdgcn_sched_barrier(0);                                        \
  }

  for (int t = 0; t < NI; ++t) {
    const int t2 = 2 * t;
    const bool s0 = (t2 + 2 < NT);     // stage tile 2t+2 (d0)
    const bool s1 = (t2 + 3 < NT);     // stage tile 2t+3 (d1)
    // p0..p3: compute tile 2t (d0); p4..p7: tile 2t+1 (d1)
    PHASE(0, 0, 0, 1, { stA(1, 1, t2 + 1); }, {});                 // p0
    PHASE(0, 1, 0, 1, { if (s0) stB(0, 0, t2 + 2); }, {});         // p1
    PHASE(0, 0, 1, 0, { if (s0) stB(0, 1, t2 + 2); }, {});         // p2
    PHASE(0, 1, 1, 0, { if (s0) stA(0, 0, t2 + 2); }, ENDV_CNT);   // p3
    PHASE(1, 0, 0, 1, { if (s0) stA(0, 1, t2 + 2); }, {});         // p4
    PHASE(1, 1, 0, 1, { if (s1) stB(1, 0, t2 + 3); }, {});         // p5
    PHASE(1, 0, 1, 0, { if (s1) stB(1, 1, t2 + 3); }, {});         // p6
    PHASE(1, 1, 1, 0, { if (s1) stA(1, 0, t2 + 3); }, ENDV_CNT);   // p7
  }
#undef PHASE
#undef ENDV_CNT

  // ---- epilogue ----
  float bs[4];
#pragma unroll
  for (int ni = 0; ni < 4; ++ni) bs[ni] = bias[n0 + wn * 64 + ni * 16 + lr];

  if constexpr (EPI == 0) {
    if (n0 >= 2048) {
      // ---- V tile: in-LDS transpose, coalesced VT write ----
      u16* ldsT = shm;                          // 128*TST u16 fits in 64KB
#pragma unroll
      for (int mi = 0; mi < 4; ++mi)
#pragma unroll
        for (int ni = 0; ni < 4; ++ni) {
          const int c = wn * 64 + ni * 16 + lr;         // 0..127
          const int r0 = wm * 64 + mi * 16 + lg * 4;    // 0..127
          ushort4 pk = { f2bf(acc[mi][ni][0] + bs[ni]),
                         f2bf(acc[mi][ni][1] + bs[ni]),
                         f2bf(acc[mi][ni][2] + bs[ni]),
                         f2bf(acc[mi][ni][3] + bs[ni]) };
          *(ushort4*)&ldsT[c * TST + r0] = pk;
        }
      __syncthreads();
      // 256 threads: each writes one 64-u16 half-row (128B) of one col
      const int b0 = m0 >> 11, s0b = m0 & 2047;
      const int cc = tid >> 1, hf = tid & 1;
      const int hd = (n0 - 2048) + cc, hh = hd >> 6, dd = hd & 63;
      u16* dst = (u16*)aux +
                 (((size_t)(b0 * 16 + hh) * 64 + dd) << 11) + s0b + hf * 64;
      const u16* srcT = &ldsT[cc * TST + hf * 64];
#pragma unroll
      for (int i2 = 0; i2 < 8; ++i2)
        *(bf16x8*)(dst + i2 * 8) = *(const bf16x8*)(srcT + i2 * 8);
      return;
    }
  }

#pragma unroll
  for (int mi = 0; mi < 4; ++mi) {
#pragma unroll
    for (int j = 0; j < 4; ++j) {
      const int rr = m0 + wm * 64 + mi * 16 + lg * 4 + j;
#pragma unroll
      for (int ni = 0; ni < 4; ++ni) {
        const int c = n0 + wn * 64 + ni * 16 + lr;
        float v = acc[mi][ni][j] + bs[ni];
        if constexpr (EPI == 0) {
          ((u16*)Cout)[(size_t)rr * 2048 + c] = f2bf(v);   // Q,K -> [T][2048]
        } else if constexpr (EPI == 1) {
          const size_t idx = (size_t)rr * N + c;
          ((float*)Cout)[idx] = v + res[idx];
        } else {
          const size_t idx = (size_t)rr * N + c;
          ((u16*)Cout)[idx] = f2bf(gelu_tanh(v));
        }
      }
    }
  }
}

// ---------------------------------------------------------------------------
// Flash attention (causal), swapped-QK + transposed-PV; 3-ring staged K/V.
// (unchanged from round 13)
// ---------------------------------------------------------------------------
__global__ __launch_bounds__(512) void attn_kernel(const u16* __restrict__ qk,
    const u16* __restrict__ vt, u16* __restrict__ obuf) {
  __shared__ __align__(16) u16 ldsK[3][64 * 64];
  __shared__ __align__(16) u16 ldsV[3][64 * 64];
  __shared__ __align__(16) u16 ldsP[8][2][16 * PST];
  const int tid = threadIdx.x, l = tid & 63, w = tid >> 6;
  const int lr = l & 15, lg = l >> 4;
  const int lid = (blockIdx.x & 7) * 32 + (blockIdx.x >> 3);   // 256 blocks
  const int bh = lid >> 2, bx = lid & 3;
  const int b = bh >> 4, h = bh & 15;
  const u16* qbase = qk + (size_t)b * SEQ * 2048 + h * 64;
  const u16* kbase = qk + (size_t)b * SEQ * 2048 + 1024 + h * 64;
  const u16* vbase = vt + (size_t)bh * 64 * SEQ;

  const int srow = tid >> 3;                     // 0..63
  const int scb  = ((tid & 7) * 16) ^ ((srow & 7) << 4);   // swizzled col bytes
  const int sel  = scb >> 1;                     // element offset in 64-col row

  auto stageKV = [&](int t) {
    const int bi = t % 3;
    gload16(kbase + (size_t)(t * 64 + srow) * 2048 + sel, &ldsK[bi][tid * 8]);
    gload16(vbase + (size_t)srow * SEQ + t * 64 + sel,    &ldsV[bi][tid * 8]);
  };

#pragma unroll
  for (int half = 0; half < 2; ++half) {
    const int qt = half ? (7 - bx) : bx;
    const int q0 = qt * 256 + w * 32;            // wave's first q row
    bf16x8 qf[2][2];
#pragma unroll
    for (int mi = 0; mi < 2; ++mi)
#pragma unroll
      for (int ks = 0; ks < 2; ++ks) {
        bf16x8 raw = *(const bf16x8*)(qbase +
            (size_t)(q0 + mi * 16 + lr) * 2048 + ks * 32 + lg * 8);
        bf16x8 sc8;
#pragma unroll
        for (int i = 0; i < 8; ++i) sc8[i] = (short)f2bf(bf2f(raw[i]) * 0.125f);
        qf[mi][ks] = sc8;
      }

    f32x4 o[2][4];
#pragma unroll
    for (int mi = 0; mi < 2; ++mi)
#pragma unroll
      for (int nd = 0; nd < 4; ++nd) o[mi][nd] = f32x4{0.f, 0.f, 0.f, 0.f};
    float m_[2] = {-1e30f, -1e30f}, ls[2] = {0.f, 0.f};

    const int nt = 4 * qt + 4;
    const int qmaxw = q0 + 31;

    stageKV(0);                                  // prologue

    for (int kt = 0; kt < nt; ++kt) {
      if (kt + 1 < nt) {
        stageKV(kt + 1);
        asm volatile("s_waitcnt vmcnt(2)" ::: "memory");   // kt landed
      } else {
        asm volatile("s_waitcnt vmcnt(0)" ::: "memory");
      }
      __builtin_amdgcn_s_barrier();              // publish kt (all waves)
      __builtin_amdgcn_sched_barrier(0);
      const u16* bK = &ldsK[kt % 3][0];
      const u16* bV = &ldsV[kt % 3][0];

      if (kt * 64 <= qmaxw) {          // wave has live rows in this k-tile
        // ---- S^T = K . Q^T  (col = q = lr, row = key) ----
        f32x4 sc[2][4];
#pragma unroll
        for (int mi = 0; mi < 2; ++mi)
#pragma unroll
          for (int ni = 0; ni < 4; ++ni) sc[mi][ni] = f32x4{0.f, 0.f, 0.f, 0.f};
#pragma unroll
        for (int ks = 0; ks < 2; ++ks)
#pragma unroll
          for (int ni = 0; ni < 4; ++ni) {
            const int r2 = ni * 16 + lr;
            const int cb = (r2 << 7) + ((ks * 64 + lg * 16) ^ ((r2 & 7) << 4));
            bf16x8 kf = *(const bf16x8*)&bK[cb >> 1];
            sc[0][ni] = __builtin_amdgcn_mfma_f32_16x16x32_bf16(kf, qf[0][ks], sc[0][ni], 0, 0, 0);
            sc[1][ni] = __builtin_amdgcn_mfma_f32_16x16x32_bf16(kf, qf[1][ks], sc[1][ni], 0, 0, 0);
          }

        // ---- causal mask ----
        if (kt * 64 + 63 > q0) {
#pragma unroll
          for (int mi = 0; mi < 2; ++mi) {
            const int qa = q0 + mi * 16 + lr;
#pragma unroll
            for (int ni = 0; ni < 4; ++ni)
#pragma unroll
              for (int j = 0; j < 4; ++j) {
                const int ka = kt * 64 + ni * 16 + lg * 4 + j;
                if (ka > qa) sc[mi][ni][j] = -1e30f;
              }
          }
        }

        // ---- online softmax (lane-local row q = lr; T13 defer-max) ----
#pragma unroll
        for (int mi = 0; mi < 2; ++mi) {
          float mx = sc[mi][0][0];
#pragma unroll
          for (int ni = 0; ni < 4; ++ni)
#pragma unroll
            for (int j = 0; j < 4; ++j) mx = fmaxf(mx, sc[mi][ni][j]);
          mx = fmaxf(mx, __shfl_xor(mx, 16, 64));
          mx = fmaxf(mx, __shfl_xor(mx, 32, 64));
          if (!__all(mx <= m_[mi] + 8.0f)) {     // rescale only when needed
            const float newm = fmaxf(m_[mi], mx);
            const float alpha = __expf(m_[mi] - newm);
            m_[mi] = newm;
            ls[mi] *= alpha;
#pragma unroll
            for (int nd = 0; nd < 4; ++nd) {
              o[mi][nd][0] *= alpha; o[mi][nd][1] *= alpha;
              o[mi][nd][2] *= alpha; o[mi][nd][3] *= alpha;
            }
          }
          float ps = 0.f;
#pragma unroll
          for (int ni = 0; ni < 4; ++ni) {
            float p0 = __expf(sc[mi][ni][0] - m_[mi]);
            float p1 = __expf(sc[mi][ni][1] - m_[mi]);
            float p2 = __expf(sc[mi][ni][2] - m_[mi]);
            float p3 = __expf(sc[mi][ni][3] - m_[mi]);
            ps += (p0 + p1) + (p2 + p3);
            u32 w0 = pk2(p0, p1), w1 = pk2(p2, p3);
            *(uint2*)&ldsP[w][mi][lr * PST + ni * 16 + lg * 4] = make_uint2(w0, w1);
          }
          ps += __shfl_xor(ps, 16, 64);          // row total (across lg)
          ps += __shfl_xor(ps, 32, 64);
          ls[mi] += ps;
        }

        // ---- O^T += V^T . P  (row = d, col = q = lr) ----
#pragma unroll
        for (int ks = 0; ks < 2; ++ks) {
          bf16x8 pf0 = *(const bf16x8*)&ldsP[w][0][lr * PST + ks * 32 + lg * 8];
          bf16x8 pf1 = *(const bf16x8*)&ldsP[w][1][lr * PST + ks * 32 + lg * 8];
#pragma unroll
          for (int nd = 0; nd < 4; ++nd) {
            const int r2 = nd * 16 + lr;
            const int cb = (r2 << 7) + ((ks * 64 + lg * 16) ^ ((r2 & 7) << 4));
            bf16x8 vf = *(const bf16x8*)&bV[cb >> 1];
            o[0][nd] = __builtin_amdgcn_mfma_f32_16x16x32_bf16(vf, pf0, o[0][nd], 0, 0, 0);
            o[1][nd] = __builtin_amdgcn_mfma_f32_16x16x32_bf16(vf, pf1, o[1][nd], 0, 0, 0);
          }
        }
      }
    }
    __builtin_amdgcn_s_barrier();     // protect bufs before next half restages

    // ---- epilogue: O^T / l ; q = lr (lane-local), d = nd*16 + lg*4 + j ----
#pragma unroll
    for (int mi = 0; mi < 2; ++mi) {
      const float inv = 1.0f / ls[mi];
      const int qrow = q0 + mi * 16 + lr;
      u16* op = obuf + (size_t)(b * SEQ + qrow) * DM + h * 64 + lg * 4;
#pragma unroll
      for (int nd = 0; nd < 4; ++nd) {
        ushort4 pk = { f2bf(o[mi][nd][0] * inv), f2bf(o[mi][nd][1] * inv),
                       f2bf(o[mi][nd][2] * inv), f2bf(o[mi][nd][3] * inv) };
        *(ushort4*)(op + nd * 16) = pk;
      }
    }
  }
}

// ---------------------------------------------------------------------------
extern "C" void kernel_launch(void* const* d_in, const int* in_sizes, int n_in,
                              void* d_out, int out_size, void* d_ws, size_t ws_size,
                              hipStream_t stream) {
  const float* x   = (const float*)d_in[0];
  const float* Wq  = (const float*)d_in[1];
  const float* bq  = (const float*)d_in[2];
  const float* Wk  = (const float*)d_in[3];
  const float* bk  = (const float*)d_in[4];
  const float* Wv  = (const float*)d_in[5];
  const float* bv  = (const float*)d_in[6];
  const float* Wo  = (const float*)d_in[7];
  const float* bo  = (const float*)d_in[8];
  const float* g1  = (const float*)d_in[9];
  const float* be1 = (const float*)d_in[10];
  const float* g2  = (const float*)d_in[11];
  const float* be2 = (const float*)d_in[12];
  const float* W1  = (const float*)d_in[13];
  const float* bf1 = (const float*)d_in[14];
  const float* W2  = (const float*)d_in[15];
  const float* bf2 = (const float*)d_in[16];
  float* out = (float*)d_out;   // also hosts x1 (post-attn residual)

  char* ws = (char*)d_ws;
  size_t off = 0;
  auto alloc = [&](size_t bytes) {
    char* p = ws + off;
    off += (bytes + 255) & ~(size_t)255;
    return p;
  };
  u16* xnB = (u16*)alloc((size_t)T_TOK * DM * 2);     // 16 MB (xn, later xn2)
  // Region D (64 MB): MHA = qkB(32) | VTg(16) | oB(16); FFN = H(64)
  u16* D    = (u16*)alloc((size_t)T_TOK * 4096 * 2);  // 64 MB
  u16* qkB  = D;                                      // [T][2048]
  u16* VTg  = D + (size_t)T_TOK * 2048;               // [B*H][64][2048]
  u16* oB   = D + (size_t)T_TOK * 3072;               // [T][1024] attn out
  u16* HB   = D;                                      // [T][4096] (FFN phase)
  u16*   WqkvB = (u16*)alloc((size_t)3072 * 1024 * 2);
  u16*   WoB   = (u16*)alloc((size_t)1024 * 1024 * 2);
  u16*   W1B   = (u16*)alloc((size_t)4096 * 1024 * 2);
  u16*   W2B   = (u16*)alloc((size_t)1024 * 4096 * 2);
  float* bqkv  = (float*)alloc(3072 * 4);

  // fused prep: LN1 + weight casts + bias concat (one launch)
  prep_kernel<<<10252, 256, 0, stream>>>(x, g1, be1, xnB,
                                         Wq, Wk, Wv, Wo, W1, W2,
                                         WqkvB, WoB, W1B, W2B,
                                         bq, bk, bv, bqkv);

  // MHA sublayer (QKV writes Q,K -> qkB and transposed V -> VTg directly)
  gemm8p<0><<<1536, 256, 0, stream>>>(xnB, WqkvB, bqkv, nullptr,
                                      qkB, VTg, T_TOK, 3072, 1024, 24);
  attn_kernel<<<256, 512, 0, stream>>>(qkB, VTg, oB);
  gemm8p<1><<<512, 256, 0, stream>>>(oB, WoB, bo, x,
                                     out, nullptr, T_TOK, 1024, 1024, 8);

  // FFN sublayer
  ln_kernel<<<T_TOK, 256, 0, stream>>>(out, g2, be2, xnB);
  gemm8p<2><<<2048, 256, 0, stream>>>(xnB, W1B, bf1, nullptr,
                                      HB, nullptr, T_TOK, 4096, 1024, 32);
  gemm8p<1><<<512, 256, 0, stream>>>(HB, W2B, bf2, out,
                                     out, nullptr, T_TOK, 1024, 4096, 8);
}

// Round 16
// 363.148 us; speedup vs baseline: 1.0105x; 1.0022x over previous
//
#include <hip/hip_runtime.h>
#include <math.h>

// ---------------------------------------------------------------------------
// Transformer encoder block, MI355X gfx950.  Round 16.
//   - GEMMs: exact round-13 configuration (best measured, 362.8 us) --
//     rounds 14/15 variants reverted (both refuted by counters).
//   - attn: paired k-tiles -- one vmcnt(4)+barrier per 2 tiles (36 -> 18 sync
//     slots per block), 6-tile K/V ring so overwrites target slots last read
//     TWO barriers back (stage-before-barrier safe; round-9 race class avoided).
// ---------------------------------------------------------------------------

typedef unsigned short u16;
typedef unsigned int u32;
typedef __attribute__((ext_vector_type(8))) short bf16x8;   // 8 bf16 = 4 VGPRs
typedef __attribute__((ext_vector_type(4))) float f32x4;

#define T_TOK 8192      // 4 * 2048 tokens
#define DM    1024      // model dim
#define SEQ   2048
#define PST   88        // attn ldsP row stride (u16)
#define TST   136       // V-transpose LDS row stride (u16)

__device__ __forceinline__ u16 f2bf(float f) {
  union { float f; unsigned int u; } c; c.f = f;
  unsigned int u = c.u + 0x7fffu + ((c.u >> 16) & 1u);   // RNE
  return (u16)(u >> 16);
}

__device__ __forceinline__ u32 pk2(float a, float b) {
  return (u32)f2bf(a) | ((u32)f2bf(b) << 16);
}

__device__ __forceinline__ float bf2f(short s) {
  union { float f; unsigned int u; } c; c.u = ((u32)(u16)s) << 16;
  return c.f;
}

__device__ __forceinline__ void gload16(const void* gp, void* lp) {
  __builtin_amdgcn_global_load_lds(
      (const __attribute__((address_space(1))) void*)gp,
      (__attribute__((address_space(3))) void*)lp, 16, 0, 0);
}

__device__ __forceinline__ float gelu_tanh(float v) {
  float u = 0.7978845608f * (v + 0.044715f * v * v * v);
  return v / (1.0f + __expf(-2.0f * u));
}

// ---------------------------------------------------------------------------
// prep_kernel: blocks [0,8192) = LN1 rows; [8192,10240) = weight casts;
//              [10240,10252) = qkv bias concat.
// ---------------------------------------------------------------------------
__global__ __launch_bounds__(256) void prep_kernel(
    const float* __restrict__ x, const float* __restrict__ g,
    const float* __restrict__ b, u16* __restrict__ xnB,
    const float* __restrict__ Wq, const float* __restrict__ Wk,
    const float* __restrict__ Wv, const float* __restrict__ Wo,
    const float* __restrict__ W1, const float* __restrict__ W2,
    u16* __restrict__ WqkvB, u16* __restrict__ WoB,
    u16* __restrict__ W1B, u16* __restrict__ W2B,
    const float* __restrict__ bq, const float* __restrict__ bk,
    const float* __restrict__ bv, float* __restrict__ bqkv) {
  __shared__ float red[4];
  const int bid = blockIdx.x, tid = threadIdx.x;
  if (bid < 8192) {
    const int l = tid & 63, w = tid >> 6;
    const size_t row = bid;
    float4 v = reinterpret_cast<const float4*>(x + row * DM)[tid];
    float s = v.x + v.y + v.z + v.w;
#pragma unroll
    for (int off = 1; off < 64; off <<= 1) s += __shfl_xor(s, off, 64);
    if (l == 0) red[w] = s;
    __syncthreads();
    float mu = (red[0] + red[1] + red[2] + red[3]) * (1.0f / 1024.0f);
    float dx = v.x - mu, dy = v.y - mu, dz = v.z - mu, dw = v.w - mu;
    float ss = dx * dx + dy * dy + dz * dz + dw * dw;
#pragma unroll
    for (int off = 1; off < 64; off <<= 1) ss += __shfl_xor(ss, off, 64);
    __syncthreads();
    if (l == 0) red[w] = ss;
    __syncthreads();
    float var = (red[0] + red[1] + red[2] + red[3]) * (1.0f / 1023.0f);
    float inv = 1.0f / (sqrtf(var) + 1e-8f);
    const int c = tid * 4;
    u16* o = xnB + row * DM + c;
    o[0] = f2bf(dx * inv * g[c + 0] + b[c + 0]);
    o[1] = f2bf(dy * inv * g[c + 1] + b[c + 1]);
    o[2] = f2bf(dz * inv * g[c + 2] + b[c + 2]);
    o[3] = f2bf(dw * inv * g[c + 3] + b[c + 3]);
  } else if (bid < 10240) {
    for (int i = (bid - 8192) * 256 + tid; i < 3145728; i += 2048 * 256) {
      const float* s; u16* d; int j;
      if (i < 262144)       { s = Wq; d = WqkvB;           j = i; }
      else if (i < 524288)  { s = Wk; d = WqkvB + 1048576; j = i - 262144; }
      else if (i < 786432)  { s = Wv; d = WqkvB + 2097152; j = i - 524288; }
      else if (i < 1048576) { s = Wo; d = WoB;             j = i - 786432; }
      else if (i < 2097152) { s = W1; d = W1B;             j = i - 1048576; }
      else                  { s = W2; d = W2B;             j = i - 2097152; }
      float4 v = reinterpret_cast<const float4*>(s)[j];
      ushort4 o = { f2bf(v.x), f2bf(v.y), f2bf(v.z), f2bf(v.w) };
      reinterpret_cast<ushort4*>(d)[j] = o;
    }
  } else {
    int i = (bid - 10240) * 256 + tid;           // 0..3071
    float val = (i < 1024) ? bq[i] : (i < 2048) ? bk[i - 1024] : bv[i - 2048];
    bqkv[i] = val;
  }
}

// ---------------------------------------------------------------------------
// LayerNorm (standalone, used for LN2)
// ---------------------------------------------------------------------------
__global__ __launch_bounds__(256) void ln_kernel(const float* __restrict__ x,
    const float* __restrict__ g, const float* __restrict__ b, u16* __restrict__ out) {
  __shared__ float red[4];
  const int tid = threadIdx.x, l = tid & 63, w = tid >> 6;
  const size_t row = blockIdx.x;
  float4 v = reinterpret_cast<const float4*>(x + row * DM)[tid];
  float s = v.x + v.y + v.z + v.w;
#pragma unroll
  for (int off = 1; off < 64; off <<= 1) s += __shfl_xor(s, off, 64);
  if (l == 0) red[w] = s;
  __syncthreads();
  float mu = (red[0] + red[1] + red[2] + red[3]) * (1.0f / 1024.0f);
  float dx = v.x - mu, dy = v.y - mu, dz = v.z - mu, dw = v.w - mu;
  float ss = dx * dx + dy * dy + dz * dz + dw * dw;
#pragma unroll
  for (int off = 1; off < 64; off <<= 1) ss += __shfl_xor(ss, off, 64);
  __syncthreads();                       // guard red[] reuse
  if (l == 0) red[w] = ss;
  __syncthreads();
  float var = (red[0] + red[1] + red[2] + red[3]) * (1.0f / 1023.0f);
  float inv = 1.0f / (sqrtf(var) + 1e-8f);
  const int c = tid * 4;
  u16* o = out + row * DM + c;
  o[0] = f2bf(dx * inv * g[c + 0] + b[c + 0]);
  o[1] = f2bf(dy * inv * g[c + 1] + b[c + 1]);
  o[2] = f2bf(dz * inv * g[c + 2] + b[c + 2]);
  o[3] = f2bf(dw * inv * g[c + 3] + b[c + 3]);
}

// ---------------------------------------------------------------------------
// gemm8p<EPI, BM>: C[M,N] = A[M,K] @ Bw[N,K]^T + bias (+res) (+gelu)
// m201-style 8-phase schedule, BK=64, 2 K-tiles per loop iteration.
// (Round-13 version, verbatim -- best measured.)
// ---------------------------------------------------------------------------
template <int EPI, int BM>
__global__ __launch_bounds__(512) void gemm8p(const u16* __restrict__ A,
    const u16* __restrict__ Bw, const float* __restrict__ bias,
    const float* res, void* Cout, void* aux, int M, int N, int K, int gx) {
  constexpr int MI  = BM / 32;                 // acc rows (8 or 4)
  constexpr int AMI = MI / 2;                  // A frags per phase (4 or 2)
  constexpr int VC  = (BM == 256) ? 6 : 5;     // counted vmcnt
  __shared__ __align__(16) u16 shm[BM * 128 + 256 * 128];
  const int tid = threadIdx.x;
  const int l = tid & 63;
  const int w = tid >> 6;
  const int wm = w >> 2, wn = w & 3;
  const int lr = l & 15, lg = l >> 4;

  // ---- XCD supertile remap (T1) ----
  const int nb = gridDim.x;
  const int q = nb >> 3, r = nb & 7;
  const int xcd = blockIdx.x & 7, jj = blockIdx.x >> 3;
  const int lid = (xcd < r ? xcd * (q + 1) : r * (q + 1) + (xcd - r) * q) + jj;
  const int stid = lid >> 5, pos = lid & 31;
  const int nstx = gx >> 2;
  const int stx = stid % nstx, sty = stid / nstx;
  const int bx = stx * 4 + (pos & 3), by = sty * 8 + (pos >> 2);
  const int m0 = by * BM, n0 = bx * 256;

  // ---- staging source (pre-swizzled): D = tid*16, L = D ^ ((D>>7)&3)<<4 ----
  const int Dl = tid * 16;
  const int Ls = Dl ^ (((Dl >> 7) & 3) << 4);
  const int srow = Ls >> 6;            // 0..127
  const int scol = (Ls & 63) >> 1;     // element col 0..31 (8-aligned)
  const u16* aS0 = A  + (size_t)(m0 + srow) * K + scol;
  const u16* aS1 = aS0 + (size_t)128 * K;          // BM==256 only
  const u16* bS0 = Bw + (size_t)(n0 + srow) * K + scol;
  const u16* bS1 = bS0 + (size_t)128 * K;

  // ---- ds_read bases (swizzled; XOR term constant per lane) ----
  const int sx = ((lr >> 1) & 3) << 4;
  const int aBase = (wm * (BM / 2) + lr) * 64 + ((lg * 16) ^ sx);  // bytes
  const int bBase = (wn * 64 + lr) * 64 + ((lg * 16) ^ sx);

  f32x4 acc[MI][4];
#pragma unroll
  for (int i = 0; i < MI; ++i)
#pragma unroll
    for (int j = 0; j < 4; ++j) acc[i][j] = f32x4{0.f, 0.f, 0.f, 0.f};
  bf16x8 bv[2][4];

  const int NT = K >> 6;               // K-tiles of 64
  const int NI = NT >> 1;              // loop iterations (2 tiles each)

  auto stA = [&](int d, int ks, int tile) {
    u16* dst = shm + (d * 2 + ks) * (BM * 32) + tid * 8;
    const int ko = tile * 64 + ks * 32;
    gload16(aS0 + ko, dst);
    if constexpr (BM == 256) gload16(aS1 + ko, dst + 4096);
  };
  auto stB = [&](int d, int ks, int tile) {
    u16* dst = shm + BM * 128 + (d * 2 + ks) * (256 * 32) + tid * 8;
    const int ko = tile * 64 + ks * 32;
    gload16(bS0 + ko, dst);
    gload16(bS1 + ko, dst + 4096);
  };

  // ---- prologue: tile0 -> d0 (4 halves), tile1 -> d1 (B0,B1,A-ks0) ----
  stB(0, 0, 0); stB(0, 1, 0); stA(0, 0, 0); stA(0, 1, 0);
  stB(1, 0, 1); stB(1, 1, 1); stA(1, 0, 1);
  asm volatile("s_waitcnt vmcnt(%0)" :: "i"(VC) : "memory");
  __builtin_amdgcn_sched_barrier(0);
  __builtin_amdgcn_s_barrier();

#define PHASE(DBUF, KS, MH, READB, STAGE, ENDV)                               \
  {                                                                           \
    const char* abuf = (const char*)(shm + ((DBUF) * 2 + (KS)) * (BM * 32));  \
    const char* bbuf =                                                        \
        (const char*)(shm + BM * 128 + ((DBUF) * 2 + (KS)) * (256 * 32));     \
    bf16x8 av[AMI];                                                           \
    _Pragma("unroll")                                                         \
    for (int i = 0; i < AMI; ++i)                                             \
      av[i] = *(const bf16x8*)(abuf + aBase + ((MH) * AMI + i) * 1024);       \
    if (READB) {                                                              \
      _Pragma("unroll")                                                       \
      for (int ni = 0; ni < 4; ++ni)                                          \
        bv[KS][ni] = *(const bf16x8*)(bbuf + bBase + ni * 1024);              \
    }                                                                         \
    STAGE;                                                                    \
    __builtin_amdgcn_s_barrier();                                             \
    asm volatile("s_waitcnt lgkmcnt(0)" ::: "memory");                        \
    __builtin_amdgcn_sched_barrier(0);                                        \
    __builtin_amdgcn_s_setprio(1);                                            \
    _Pragma("unroll")                                                         \
    for (int i = 0; i < AMI; ++i)                                             \
      _Pragma("unroll")                                                       \
      for (int ni = 0; ni < 4; ++ni)                                          \
        acc[(MH) * AMI + i][ni] = __builtin_amdgcn_mfma_f32_16x16x32_bf16(    \
            av[i], bv[KS][ni], acc[(MH) * AMI + i][ni], 0, 0, 0);             \
    __builtin_amdgcn_s_setprio(0);                                            \
    ENDV;                                                                     \
    __builtin_amdgcn_s_barrier();                                             \
  }

#define ENDV_CNT                                                              \
  {                                                                           \
    if (t + 1 < NI) {                                                         \
      asm volatile("s_waitcnt vmcnt(%0)" :: "i"(VC) : "memory");              \
    } else {                                                                  \
      asm volatile("s_waitcnt vmcnt(0)" ::: "memory");                        \
    }                                                                         \
    __builtin_amdgcn_sched_barrier(0);                                        \
  }

  for (int t = 0; t < NI; ++t) {
    const int t2 = 2 * t;
    const bool s0 = (t2 + 2 < NT);     // stage tile 2t+2 (d0)
    const bool s1 = (t2 + 3 < NT);     // stage tile 2t+3 (d1)
    // p0..p3: compute tile 2t (d0); p4..p7: tile 2t+1 (d1)
    PHASE(0, 0, 0, 1, { stA(1, 1, t2 + 1); }, {});                 // p0
    PHASE(0, 1, 0, 1, { if (s0) stB(0, 0, t2 + 2); }, {});         // p1
    PHASE(0, 0, 1, 0, { if (s0) stB(0, 1, t2 + 2); }, {});         // p2
    PHASE(0, 1, 1, 0, { if (s0) stA(0, 0, t2 + 2); }, ENDV_CNT);   // p3
    PHASE(1, 0, 0, 1, { if (s0) stA(0, 1, t2 + 2); }, {});         // p4
    PHASE(1, 1, 0, 1, { if (s1) stB(1, 0, t2 + 3); }, {});         // p5
    PHASE(1, 0, 1, 0, { if (s1) stB(1, 1, t2 + 3); }, {});         // p6
    PHASE(1, 1, 1, 0, { if (s1) stA(1, 0, t2 + 3); }, ENDV_CNT);   // p7
  }
#undef PHASE
#undef ENDV_CNT

  // ---- epilogue ----
  float bs[4];
#pragma unroll
  for (int ni = 0; ni < 4; ++ni) bs[ni] = bias[n0 + wn * 64 + ni * 16 + lr];

  if constexpr (EPI == 0) {
    if (n0 >= 2048) {
      // ---- V tile: in-LDS transpose, coalesced VT write ----
      u16* ldsT = shm;                          // 256*TST u16 fits
#pragma unroll
      for (int mi = 0; mi < MI; ++mi)
#pragma unroll
        for (int ni = 0; ni < 4; ++ni) {
          const int c = wn * 64 + ni * 16 + lr;
          const int r0 = wm * (BM / 2) + mi * 16 + lg * 4;
          ushort4 pk = { f2bf(acc[mi][ni][0] + bs[ni]),
                         f2bf(acc[mi][ni][1] + bs[ni]),
                         f2bf(acc[mi][ni][2] + bs[ni]),
                         f2bf(acc[mi][ni][3] + bs[ni]) };
          *(ushort4*)&ldsT[c * TST + r0] = pk;
        }
      __syncthreads();
      const int b0 = m0 >> 11, s0b = m0 & 2047;
      const int cc = tid >> 1, hf = tid & 1;
      const int hd = (n0 - 2048) + cc, hh = hd >> 6, dd = hd & 63;
      u16* dst = (u16*)aux +
                 (((size_t)(b0 * 16 + hh) * 64 + dd) << 11) + s0b + hf * 64;
      const u16* srcT = &ldsT[cc * TST + hf * 64];
#pragma unroll
      for (int i2 = 0; i2 < 8; ++i2)
        *(bf16x8*)(dst + i2 * 8) = *(const bf16x8*)(srcT + i2 * 8);
      return;
    }
  }

#pragma unroll
  for (int mi = 0; mi < MI; ++mi) {
#pragma unroll
    for (int j = 0; j < 4; ++j) {
      const int rr = m0 + wm * (BM / 2) + mi * 16 + lg * 4 + j;
#pragma unroll
      for (int ni = 0; ni < 4; ++ni) {
        const int c = n0 + wn * 64 + ni * 16 + lr;
        float v = acc[mi][ni][j] + bs[ni];
        if constexpr (EPI == 0) {
          ((u16*)Cout)[(size_t)rr * 2048 + c] = f2bf(v);   // Q,K -> [T][2048]
        } else if constexpr (EPI == 1) {
          const size_t idx = (size_t)rr * N + c;
          ((float*)Cout)[idx] = v + res[idx];
        } else {
          const size_t idx = (size_t)rr * N + c;
          ((u16*)Cout)[idx] = f2bf(gelu_tanh(v));
        }
      }
    }
  }
}

// ---------------------------------------------------------------------------
// Flash attention (causal), swapped-QK + transposed-PV.
// NEW: paired k-tiles (one vmcnt(4)+barrier per 2 tiles) with a 6-tile K/V
// ring: overwritten slots were last read two barriers back (race-safe with
// stage-issued-before-barrier).
// ---------------------------------------------------------------------------
__global__ __launch_bounds__(512) void attn_kernel(const u16* __restrict__ qk,
    const u16* __restrict__ vt, u16* __restrict__ obuf) {
  __shared__ __align__(16) u16 ldsK[6][64 * 64];
  __shared__ __align__(16) u16 ldsV[6][64 * 64];
  __shared__ __align__(16) u16 ldsP[8][2][16 * PST];
  const int tid = threadIdx.x, l = tid & 63, w = tid >> 6;
  const int lr = l & 15, lg = l >> 4;
  const int lid = (blockIdx.x & 7) * 32 + (blockIdx.x >> 3);   // 256 blocks
  const int bh = lid >> 2, bx = lid & 3;
  const int b = bh >> 4, h = bh & 15;
  const u16* qbase = qk + (size_t)b * SEQ * 2048 + h * 64;
  const u16* kbase = qk + (size_t)b * SEQ * 2048 + 1024 + h * 64;
  const u16* vbase = vt + (size_t)bh * 64 * SEQ;

  const int srow = tid >> 3;                     // 0..63
  const int scb  = ((tid & 7) * 16) ^ ((srow & 7) << 4);   // swizzled col bytes
  const int sel  = scb >> 1;                     // element offset in 64-col row

  auto stageKV = [&](int t) {
    const int bi = t % 6;
    gload16(kbase + (size_t)(t * 64 + srow) * 2048 + sel, &ldsK[bi][tid * 8]);
    gload16(vbase + (size_t)srow * SEQ + t * 64 + sel,    &ldsV[bi][tid * 8]);
  };

#pragma unroll
  for (int half = 0; half < 2; ++half) {
    const int qt = half ? (7 - bx) : bx;
    const int q0 = qt * 256 + w * 32;            // wave's first q row
    bf16x8 qf[2][2];
#pragma unroll
    for (int mi = 0; mi < 2; ++mi)
#pragma unroll
      for (int ks = 0; ks < 2; ++ks) {
        bf16x8 raw = *(const bf16x8*)(qbase +
            (size_t)(q0 + mi * 16 + lr) * 2048 + ks * 32 + lg * 8);
        bf16x8 sc8;
#pragma unroll
        for (int i = 0; i < 8; ++i) sc8[i] = (short)f2bf(bf2f(raw[i]) * 0.125f);
        qf[mi][ks] = sc8;
      }

    f32x4 o[2][4];
#pragma unroll
    for (int mi = 0; mi < 2; ++mi)
#pragma unroll
      for (int nd = 0; nd < 4; ++nd) o[mi][nd] = f32x4{0.f, 0.f, 0.f, 0.f};
    float m_[2] = {-1e30f, -1e30f}, ls[2] = {0.f, 0.f};

    const int nt = 4 * qt + 4;                   // always even
    const int nip = nt >> 1;                     // paired iterations
    const int qmaxw = q0 + 31;

    stageKV(0); stageKV(1);                      // prologue (4 loads)

    for (int jt = 0; jt < nip; ++jt) {
      const int k0t = 2 * jt;
      if (jt + 1 < nip) {
        stageKV(k0t + 2); stageKV(k0t + 3);      // into slots read 2 bars ago
        asm volatile("s_waitcnt vmcnt(4)" ::: "memory");   // k0t,k0t+1 landed
      } else {
        asm volatile("s_waitcnt vmcnt(0)" ::: "memory");
      }
      __builtin_amdgcn_s_barrier();              // publish pair (all waves)
      __builtin_amdgcn_sched_barrier(0);

#pragma unroll
      for (int sub = 0; sub < 2; ++sub) {
        const int kt = k0t + sub;
        const u16* bK = &ldsK[kt % 6][0];
        const u16* bV = &ldsV[kt % 6][0];

        if (kt * 64 <= qmaxw) {        // wave has live rows in this k-tile
          // ---- S^T = K . Q^T  (col = q = lr, row = key) ----
          f32x4 sc[2][4];
#pragma unroll
          for (int mi = 0; mi < 2; ++mi)
#pragma unroll
            for (int ni = 0; ni < 4; ++ni) sc[mi][ni] = f32x4{0.f, 0.f, 0.f, 0.f};
#pragma unroll
          for (int ks = 0; ks < 2; ++ks)
#pragma unroll
            for (int ni = 0; ni < 4; ++ni) {
              const int r2 = ni * 16 + lr;
              const int cb = (r2 << 7) + ((ks * 64 + lg * 16) ^ ((r2 & 7) << 4));
              bf16x8 kf = *(const bf16x8*)&bK[cb >> 1];
              sc[0][ni] = __builtin_amdgcn_mfma_f32_16x16x32_bf16(kf, qf[0][ks], sc[0][ni], 0, 0, 0);
              sc[1][ni] = __builtin_amdgcn_mfma_f32_16x16x32_bf16(kf, qf[1][ks], sc[1][ni], 0, 0, 0);
            }

          // ---- causal mask ----
          if (kt * 64 + 63 > q0) {
#pragma unroll
            for (int mi = 0; mi < 2; ++mi) {
              const int qa = q0 + mi * 16 + lr;
#pragma unroll
              for (int ni = 0; ni < 4; ++ni)
#pragma unroll
                for (int j = 0; j < 4; ++j) {
                  const int ka = kt * 64 + ni * 16 + lg * 4 + j;
                  if (ka > qa) sc[mi][ni][j] = -1e30f;
                }
            }
          }

          // ---- online softmax (lane-local row q = lr; T13 defer-max) ----
#pragma unroll
          for (int mi = 0; mi < 2; ++mi) {
            float mx = sc[mi][0][0];
#pragma unroll
            for (int ni = 0; ni < 4; ++ni)
#pragma unroll
              for (int j = 0; j < 4; ++j) mx = fmaxf(mx, sc[mi][ni][j]);
            mx = fmaxf(mx, __shfl_xor(mx, 16, 64));
            mx = fmaxf(mx, __shfl_xor(mx, 32, 64));
            if (!__all(mx <= m_[mi] + 8.0f)) {   // rescale only when needed
              const float newm = fmaxf(m_[mi], mx);
              const float alpha = __expf(m_[mi] - newm);
              m_[mi] = newm;
              ls[mi] *= alpha;
#pragma unroll
              for (int nd = 0; nd < 4; ++nd) {
                o[mi][nd][0] *= alpha; o[mi][nd][1] *= alpha;
                o[mi][nd][2] *= alpha; o[mi][nd][3] *= alpha;
              }
            }
            float ps = 0.f;
#pragma unroll
            for (int ni = 0; ni < 4; ++ni) {
              float p0 = __expf(sc[mi][ni][0] - m_[mi]);
              float p1 = __expf(sc[mi][ni][1] - m_[mi]);
              float p2 = __expf(sc[mi][ni][2] - m_[mi]);
              float p3 = __expf(sc[mi][ni][3] - m_[mi]);
              ps += (p0 + p1) + (p2 + p3);
              u32 w0 = pk2(p0, p1), w1 = pk2(p2, p3);
              *(uint2*)&ldsP[w][mi][lr * PST + ni * 16 + lg * 4] = make_uint2(w0, w1);
            }
            ps += __shfl_xor(ps, 16, 64);        // row total (across lg)
            ps += __shfl_xor(ps, 32, 64);
            ls[mi] += ps;
          }

          // ---- O^T += V^T . P  (row = d, col = q = lr) ----
#pragma unroll
          for (int ks = 0; ks < 2; ++ks) {
            bf16x8 pf0 = *(const bf16x8*)&ldsP[w][0][lr * PST + ks * 32 + lg * 8];
            bf16x8 pf1 = *(const bf16x8*)&ldsP[w][1][lr * PST + ks * 32 + lg * 8];
#pragma unroll
            for (int nd = 0; nd < 4; ++nd) {
              const int r2 = nd * 16 + lr;
              const int cb = (r2 << 7) + ((ks * 64 + lg * 16) ^ ((r2 & 7) << 4));
              bf16x8 vf = *(const bf16x8*)&bV[cb >> 1];
              o[0][nd] = __builtin_amdgcn_mfma_f32_16x16x32_bf16(vf, pf0, o[0][nd], 0, 0, 0);
              o[1][nd] = __builtin_amdgcn_mfma_f32_16x16x32_bf16(vf, pf1, o[1][nd], 0, 0, 0);
            }
          }
        }
      }
    }
    __builtin_amdgcn_s_barrier();     // protect ring before next half restages

    // ---- epilogue: O^T / l ; q = lr (lane-local), d = nd*16 + lg*4 + j ----
#pragma unroll
    for (int mi = 0; mi < 2; ++mi) {
      const float inv = 1.0f / ls[mi];
      const int qrow = q0 + mi * 16 + lr;
      u16* op = obuf + (size_t)(b * SEQ + qrow) * DM + h * 64 + lg * 4;
#pragma unroll
      for (int nd = 0; nd < 4; ++nd) {
        ushort4 pk = { f2bf(o[mi][nd][0] * inv), f2bf(o[mi][nd][1] * inv),
                       f2bf(o[mi][nd][2] * inv), f2bf(o[mi][nd][3] * inv) };
        *(ushort4*)(op + nd * 16) = pk;
      }
    }
  }
}

// ---------------------------------------------------------------------------
extern "C" void kernel_launch(void* const* d_in, const int* in_sizes, int n_in,
                              void* d_out, int out_size, void* d_ws, size_t ws_size,
                              hipStream_t stream) {
  const float* x   = (const float*)d_in[0];
  const float* Wq  = (const float*)d_in[1];
  const float* bq  = (const float*)d_in[2];
  const float* Wk  = (const float*)d_in[3];
  const float* bk  = (const float*)d_in[4];
  const float* Wv  = (const float*)d_in[5];
  const float* bv  = (const float*)d_in[6];
  const float* Wo  = (const float*)d_in[7];
  const float* bo  = (const float*)d_in[8];
  const float* g1  = (const float*)d_in[9];
  const float* be1 = (const float*)d_in[10];
  const float* g2  = (const float*)d_in[11];
  const float* be2 = (const float*)d_in[12];
  const float* W1  = (const float*)d_in[13];
  const float* bf1 = (const float*)d_in[14];
  const float* W2  = (const float*)d_in[15];
  const float* bf2 = (const float*)d_in[16];
  float* out = (float*)d_out;   // also hosts x1 (post-attn residual)

  char* ws = (char*)d_ws;
  size_t off = 0;
  auto alloc = [&](size_t bytes) {
    char* p = ws + off;
    off += (bytes + 255) & ~(size_t)255;
    return p;
  };
  u16* xnB = (u16*)alloc((size_t)T_TOK * DM * 2);     // 16 MB (xn, later xn2)
  // Region D (64 MB): MHA = qkB(32) | VTg(16) | oB(16); FFN = H(64)
  u16* D    = (u16*)alloc((size_t)T_TOK * 4096 * 2);  // 64 MB
  u16* qkB  = D;                                      // [T][2048]
  u16* VTg  = D + (size_t)T_TOK * 2048;               // [B*H][64][2048]
  u16* oB   = D + (size_t)T_TOK * 3072;               // [T][1024] attn out
  u16* HB   = D;                                      // [T][4096] (FFN phase)
  u16*   WqkvB = (u16*)alloc((size_t)3072 * 1024 * 2);
  u16*   WoB   = (u16*)alloc((size_t)1024 * 1024 * 2);
  u16*   W1B   = (u16*)alloc((size_t)4096 * 1024 * 2);
  u16*   W2B   = (u16*)alloc((size_t)1024 * 4096 * 2);
  float* bqkv  = (float*)alloc(3072 * 4);

  // fused prep: LN1 + weight casts + bias concat (one launch)
  prep_kernel<<<10252, 256, 0, stream>>>(x, g1, be1, xnB,
                                         Wq, Wk, Wv, Wo, W1, W2,
                                         WqkvB, WoB, W1B, W2B,
                                         bq, bk, bv, bqkv);

  // MHA sublayer (QKV writes Q,K -> qkB and transposed V -> VTg directly)
  gemm8p<0, 128><<<768, 512, 0, stream>>>(xnB, WqkvB, bqkv, nullptr,
                                          qkB, VTg, T_TOK, 3072, 1024, 12);
  attn_kernel<<<256, 512, 0, stream>>>(qkB, VTg, oB);
  gemm8p<1, 128><<<256, 512, 0, stream>>>(oB, WoB, bo, x,
                                          out, nullptr, T_TOK, 1024, 1024, 4);

  // FFN sublayer
  ln_kernel<<<T_TOK, 256, 0, stream>>>(out, g2, be2, xnB);
  gemm8p<2, 256><<<512, 512, 0, stream>>>(xnB, W1B, bf1, nullptr,
                                          HB, nullptr, T_TOK, 4096, 1024, 16);
  gemm8p<1, 128><<<256, 512, 0, stream>>>(HB, W2B, bf2, out,
                                          out, nullptr, T_TOK, 1024, 4096, 4);
}

// Round 17
// 344.655 us; speedup vs baseline: 1.0648x; 1.0537x over previous
//
#include <hip/hip_runtime.h>
#include <math.h>

// ---------------------------------------------------------------------------
// Transformer encoder block, MI355X gfx950.  Round 17: bf16 residual path.
//   - x1 (post-attn residual) stored as bf16 (x1B, 16 MB) instead of f32
//     d_out: Wo write, LN2 read, FFN2 residual read all halve (-48 MB).
//     EPI=1 -> bf16 x1 out; new EPI=3 -> f32 final out with bf16 residual;
//     ln_kernel_b = bf16-input LayerNorm.
//   - GEMM K-loop / attn / prep: round-16 configuration (plateau-verified).
// ---------------------------------------------------------------------------

typedef unsigned short u16;
typedef unsigned int u32;
typedef __attribute__((ext_vector_type(8))) short bf16x8;   // 8 bf16 = 4 VGPRs
typedef __attribute__((ext_vector_type(4))) float f32x4;

#define T_TOK 8192      // 4 * 2048 tokens
#define DM    1024      // model dim
#define SEQ   2048
#define PST   88        // attn ldsP row stride (u16)
#define TST   136       // V-transpose LDS row stride (u16)

__device__ __forceinline__ u16 f2bf(float f) {
  union { float f; unsigned int u; } c; c.f = f;
  unsigned int u = c.u + 0x7fffu + ((c.u >> 16) & 1u);   // RNE
  return (u16)(u >> 16);
}

__device__ __forceinline__ u32 pk2(float a, float b) {
  return (u32)f2bf(a) | ((u32)f2bf(b) << 16);
}

__device__ __forceinline__ float bf2f(short s) {
  union { float f; unsigned int u; } c; c.u = ((u32)(u16)s) << 16;
  return c.f;
}

__device__ __forceinline__ void gload16(const void* gp, void* lp) {
  __builtin_amdgcn_global_load_lds(
      (const __attribute__((address_space(1))) void*)gp,
      (__attribute__((address_space(3))) void*)lp, 16, 0, 0);
}

__device__ __forceinline__ float gelu_tanh(float v) {
  float u = 0.7978845608f * (v + 0.044715f * v * v * v);
  return v / (1.0f + __expf(-2.0f * u));
}

// ---------------------------------------------------------------------------
// prep_kernel: blocks [0,8192) = LN1 rows; [8192,10240) = weight casts;
//              [10240,10252) = qkv bias concat.
// ---------------------------------------------------------------------------
__global__ __launch_bounds__(256) void prep_kernel(
    const float* __restrict__ x, const float* __restrict__ g,
    const float* __restrict__ b, u16* __restrict__ xnB,
    const float* __restrict__ Wq, const float* __restrict__ Wk,
    const float* __restrict__ Wv, const float* __restrict__ Wo,
    const float* __restrict__ W1, const float* __restrict__ W2,
    u16* __restrict__ WqkvB, u16* __restrict__ WoB,
    u16* __restrict__ W1B, u16* __restrict__ W2B,
    const float* __restrict__ bq, const float* __restrict__ bk,
    const float* __restrict__ bv, float* __restrict__ bqkv) {
  __shared__ float red[4];
  const int bid = blockIdx.x, tid = threadIdx.x;
  if (bid < 8192) {
    const int l = tid & 63, w = tid >> 6;
    const size_t row = bid;
    float4 v = reinterpret_cast<const float4*>(x + row * DM)[tid];
    float s = v.x + v.y + v.z + v.w;
#pragma unroll
    for (int off = 1; off < 64; off <<= 1) s += __shfl_xor(s, off, 64);
    if (l == 0) red[w] = s;
    __syncthreads();
    float mu = (red[0] + red[1] + red[2] + red[3]) * (1.0f / 1024.0f);
    float dx = v.x - mu, dy = v.y - mu, dz = v.z - mu, dw = v.w - mu;
    float ss = dx * dx + dy * dy + dz * dz + dw * dw;
#pragma unroll
    for (int off = 1; off < 64; off <<= 1) ss += __shfl_xor(ss, off, 64);
    __syncthreads();
    if (l == 0) red[w] = ss;
    __syncthreads();
    float var = (red[0] + red[1] + red[2] + red[3]) * (1.0f / 1023.0f);
    float inv = 1.0f / (sqrtf(var) + 1e-8f);
    const int c = tid * 4;
    u16* o = xnB + row * DM + c;
    o[0] = f2bf(dx * inv * g[c + 0] + b[c + 0]);
    o[1] = f2bf(dy * inv * g[c + 1] + b[c + 1]);
    o[2] = f2bf(dz * inv * g[c + 2] + b[c + 2]);
    o[3] = f2bf(dw * inv * g[c + 3] + b[c + 3]);
  } else if (bid < 10240) {
    for (int i = (bid - 8192) * 256 + tid; i < 3145728; i += 2048 * 256) {
      const float* s; u16* d; int j;
      if (i < 262144)       { s = Wq; d = WqkvB;           j = i; }
      else if (i < 524288)  { s = Wk; d = WqkvB + 1048576; j = i - 262144; }
      else if (i < 786432)  { s = Wv; d = WqkvB + 2097152; j = i - 524288; }
      else if (i < 1048576) { s = Wo; d = WoB;             j = i - 786432; }
      else if (i < 2097152) { s = W1; d = W1B;             j = i - 1048576; }
      else                  { s = W2; d = W2B;             j = i - 2097152; }
      float4 v = reinterpret_cast<const float4*>(s)[j];
      ushort4 o = { f2bf(v.x), f2bf(v.y), f2bf(v.z), f2bf(v.w) };
      reinterpret_cast<ushort4*>(d)[j] = o;
    }
  } else {
    int i = (bid - 10240) * 256 + tid;           // 0..3071
    float val = (i < 1024) ? bq[i] : (i < 2048) ? bk[i - 1024] : bv[i - 2048];
    bqkv[i] = val;
  }
}

// ---------------------------------------------------------------------------
// LayerNorm, bf16 input (used for LN2 on x1B)
// ---------------------------------------------------------------------------
__global__ __launch_bounds__(256) void ln_kernel_b(const u16* __restrict__ x,
    const float* __restrict__ g, const float* __restrict__ b, u16* __restrict__ out) {
  __shared__ float red[4];
  const int tid = threadIdx.x, l = tid & 63, w = tid >> 6;
  const size_t row = blockIdx.x;
  ushort4 raw = reinterpret_cast<const ushort4*>(x + row * DM)[tid];
  float vx = bf2f((short)raw.x), vy = bf2f((short)raw.y);
  float vz = bf2f((short)raw.z), vw = bf2f((short)raw.w);
  float s = vx + vy + vz + vw;
#pragma unroll
  for (int off = 1; off < 64; off <<= 1) s += __shfl_xor(s, off, 64);
  if (l == 0) red[w] = s;
  __syncthreads();
  float mu = (red[0] + red[1] + red[2] + red[3]) * (1.0f / 1024.0f);
  float dx = vx - mu, dy = vy - mu, dz = vz - mu, dw = vw - mu;
  float ss = dx * dx + dy * dy + dz * dz + dw * dw;
#pragma unroll
  for (int off = 1; off < 64; off <<= 1) ss += __shfl_xor(ss, off, 64);
  __syncthreads();
  if (l == 0) red[w] = ss;
  __syncthreads();
  float var = (red[0] + red[1] + red[2] + red[3]) * (1.0f / 1023.0f);
  float inv = 1.0f / (sqrtf(var) + 1e-8f);
  const int c = tid * 4;
  u16* o = out + row * DM + c;
  o[0] = f2bf(dx * inv * g[c + 0] + b[c + 0]);
  o[1] = f2bf(dy * inv * g[c + 1] + b[c + 1]);
  o[2] = f2bf(dz * inv * g[c + 2] + b[c + 2]);
  o[3] = f2bf(dw * inv * g[c + 3] + b[c + 3]);
}

// ---------------------------------------------------------------------------
// gemm8p<EPI, BM>: C[M,N] = A[M,K] @ Bw[N,K]^T + bias (+res) (+gelu)
// m201-style 8-phase schedule, BK=64, 2 K-tiles per loop iteration.
// EPI 0: QKV (Q,K -> Cout [T][2048]; V tile -> in-LDS transpose -> aux VT).
// EPI 1: bf16 out (bias + f32 res)      [Wo -> x1B]
// EPI 2: bf16 out (bias + gelu)         [FFN1 -> H]
// EPI 3: f32 out (bias + bf16 res)      [FFN2 -> d_out]
// ---------------------------------------------------------------------------
template <int EPI, int BM>
__global__ __launch_bounds__(512) void gemm8p(const u16* __restrict__ A,
    const u16* __restrict__ Bw, const float* __restrict__ bias,
    const float* res, void* Cout, void* aux, int M, int N, int K, int gx) {
  constexpr int MI  = BM / 32;                 // acc rows (8 or 4)
  constexpr int AMI = MI / 2;                  // A frags per phase (4 or 2)
  constexpr int VC  = (BM == 256) ? 6 : 5;     // counted vmcnt
  __shared__ __align__(16) u16 shm[BM * 128 + 256 * 128];
  const int tid = threadIdx.x;
  const int l = tid & 63;
  const int w = tid >> 6;
  const int wm = w >> 2, wn = w & 3;
  const int lr = l & 15, lg = l >> 4;

  // ---- XCD supertile remap (T1) ----
  const int nb = gridDim.x;
  const int q = nb >> 3, r = nb & 7;
  const int xcd = blockIdx.x & 7, jj = blockIdx.x >> 3;
  const int lid = (xcd < r ? xcd * (q + 1) : r * (q + 1) + (xcd - r) * q) + jj;
  const int stid = lid >> 5, pos = lid & 31;
  const int nstx = gx >> 2;
  const int stx = stid % nstx, sty = stid / nstx;
  const int bx = stx * 4 + (pos & 3), by = sty * 8 + (pos >> 2);
  const int m0 = by * BM, n0 = bx * 256;

  // ---- staging source (pre-swizzled): D = tid*16, L = D ^ ((D>>7)&3)<<4 ----
  const int Dl = tid * 16;
  const int Ls = Dl ^ (((Dl >> 7) & 3) << 4);
  const int srow = Ls >> 6;            // 0..127
  const int scol = (Ls & 63) >> 1;     // element col 0..31 (8-aligned)
  const u16* aS0 = A  + (size_t)(m0 + srow) * K + scol;
  const u16* aS1 = aS0 + (size_t)128 * K;          // BM==256 only
  const u16* bS0 = Bw + (size_t)(n0 + srow) * K + scol;
  const u16* bS1 = bS0 + (size_t)128 * K;

  // ---- ds_read bases (swizzled; XOR term constant per lane) ----
  const int sx = ((lr >> 1) & 3) << 4;
  const int aBase = (wm * (BM / 2) + lr) * 64 + ((lg * 16) ^ sx);  // bytes
  const int bBase = (wn * 64 + lr) * 64 + ((lg * 16) ^ sx);

  f32x4 acc[MI][4];
#pragma unroll
  for (int i = 0; i < MI; ++i)
#pragma unroll
    for (int j = 0; j < 4; ++j) acc[i][j] = f32x4{0.f, 0.f, 0.f, 0.f};
  bf16x8 bv[2][4];

  const int NT = K >> 6;               // K-tiles of 64
  const int NI = NT >> 1;              // loop iterations (2 tiles each)

  auto stA = [&](int d, int ks, int tile) {
    u16* dst = shm + (d * 2 + ks) * (BM * 32) + tid * 8;
    const int ko = tile * 64 + ks * 32;
    gload16(aS0 + ko, dst);
    if constexpr (BM == 256) gload16(aS1 + ko, dst + 4096);
  };
  auto stB = [&](int d, int ks, int tile) {
    u16* dst = shm + BM * 128 + (d * 2 + ks) * (256 * 32) + tid * 8;
    const int ko = tile * 64 + ks * 32;
    gload16(bS0 + ko, dst);
    gload16(bS1 + ko, dst + 4096);
  };

  // ---- prologue: tile0 -> d0 (4 halves), tile1 -> d1 (B0,B1,A-ks0) ----
  stB(0, 0, 0); stB(0, 1, 0); stA(0, 0, 0); stA(0, 1, 0);
  stB(1, 0, 1); stB(1, 1, 1); stA(1, 0, 1);
  asm volatile("s_waitcnt vmcnt(%0)" :: "i"(VC) : "memory");
  __builtin_amdgcn_sched_barrier(0);
  __builtin_amdgcn_s_barrier();

#define PHASE(DBUF, KS, MH, READB, STAGE, ENDV)                               \
  {                                                                           \
    const char* abuf = (const char*)(shm + ((DBUF) * 2 + (KS)) * (BM * 32));  \
    const char* bbuf =                                                        \
        (const char*)(shm + BM * 128 + ((DBUF) * 2 + (KS)) * (256 * 32));     \
    bf16x8 av[AMI];                                                           \
    _Pragma("unroll")                                                         \
    for (int i = 0; i < AMI; ++i)                                             \
      av[i] = *(const bf16x8*)(abuf + aBase + ((MH) * AMI + i) * 1024);       \
    if (READB) {                                                              \
      _Pragma("unroll")                                                       \
      for (int ni = 0; ni < 4; ++ni)                                          \
        bv[KS][ni] = *(const bf16x8*)(bbuf + bBase + ni * 1024);              \
    }                                                                         \
    STAGE;                                                                    \
    __builtin_amdgcn_s_barrier();                                             \
    asm volatile("s_waitcnt lgkmcnt(0)" ::: "memory");                        \
    __builtin_amdgcn_sched_barrier(0);                                        \
    __builtin_amdgcn_s_setprio(1);                                            \
    _Pragma("unroll")                                                         \
    for (int i = 0; i < AMI; ++i)                                             \
      _Pragma("unroll")                                                       \
      for (int ni = 0; ni < 4; ++ni)                                          \
        acc[(MH) * AMI + i][ni] = __builtin_amdgcn_mfma_f32_16x16x32_bf16(    \
            av[i], bv[KS][ni], acc[(MH) * AMI + i][ni], 0, 0, 0);             \
    __builtin_amdgcn_s_setprio(0);                                            \
    ENDV;                                                                     \
    __builtin_amdgcn_s_barrier();                                             \
  }

#define ENDV_CNT                                                              \
  {                                                                           \
    if (t + 1 < NI) {                                                         \
      asm volatile("s_waitcnt vmcnt(%0)" :: "i"(VC) : "memory");              \
    } else {                                                                  \
      asm volatile("s_waitcnt vmcnt(0)" ::: "memory");                        \
    }                                                                         \
    __builtin_amdgcn_sched_barrier(0);                                        \
  }

  for (int t = 0; t < NI; ++t) {
    const int t2 = 2 * t;
    const bool s0 = (t2 + 2 < NT);     // stage tile 2t+2 (d0)
    const bool s1 = (t2 + 3 < NT);     // stage tile 2t+3 (d1)
    // p0..p3: compute tile 2t (d0); p4..p7: tile 2t+1 (d1)
    PHASE(0, 0, 0, 1, { stA(1, 1, t2 + 1); }, {});                 // p0
    PHASE(0, 1, 0, 1, { if (s0) stB(0, 0, t2 + 2); }, {});         // p1
    PHASE(0, 0, 1, 0, { if (s0) stB(0, 1, t2 + 2); }, {});         // p2
    PHASE(0, 1, 1, 0, { if (s0) stA(0, 0, t2 + 2); }, ENDV_CNT);   // p3
    PHASE(1, 0, 0, 1, { if (s0) stA(0, 1, t2 + 2); }, {});         // p4
    PHASE(1, 1, 0, 1, { if (s1) stB(1, 0, t2 + 3); }, {});         // p5
    PHASE(1, 0, 1, 0, { if (s1) stB(1, 1, t2 + 3); }, {});         // p6
    PHASE(1, 1, 1, 0, { if (s1) stA(1, 0, t2 + 3); }, ENDV_CNT);   // p7
  }
#undef PHASE
#undef ENDV_CNT

  // ---- epilogue ----
  float bs[4];
#pragma unroll
  for (int ni = 0; ni < 4; ++ni) bs[ni] = bias[n0 + wn * 64 + ni * 16 + lr];

  if constexpr (EPI == 0) {
    if (n0 >= 2048) {
      // ---- V tile: in-LDS transpose, coalesced VT write ----
      u16* ldsT = shm;                          // 256*TST u16 fits
#pragma unroll
      for (int mi = 0; mi < MI; ++mi)
#pragma unroll
        for (int ni = 0; ni < 4; ++ni) {
          const int c = wn * 64 + ni * 16 + lr;
          const int r0 = wm * (BM / 2) + mi * 16 + lg * 4;
          ushort4 pk = { f2bf(acc[mi][ni][0] + bs[ni]),
                         f2bf(acc[mi][ni][1] + bs[ni]),
                         f2bf(acc[mi][ni][2] + bs[ni]),
                         f2bf(acc[mi][ni][3] + bs[ni]) };
          *(ushort4*)&ldsT[c * TST + r0] = pk;
        }
      __syncthreads();
      const int b0 = m0 >> 11, s0b = m0 & 2047;
      const int cc = tid >> 1, hf = tid & 1;
      const int hd = (n0 - 2048) + cc, hh = hd >> 6, dd = hd & 63;
      u16* dst = (u16*)aux +
                 (((size_t)(b0 * 16 + hh) * 64 + dd) << 11) + s0b + hf * 64;
      const u16* srcT = &ldsT[cc * TST + hf * 64];
#pragma unroll
      for (int i2 = 0; i2 < 8; ++i2)
        *(bf16x8*)(dst + i2 * 8) = *(const bf16x8*)(srcT + i2 * 8);
      return;
    }
  }

#pragma unroll
  for (int mi = 0; mi < MI; ++mi) {
#pragma unroll
    for (int j = 0; j < 4; ++j) {
      const int rr = m0 + wm * (BM / 2) + mi * 16 + lg * 4 + j;
#pragma unroll
      for (int ni = 0; ni < 4; ++ni) {
        const int c = n0 + wn * 64 + ni * 16 + lr;
        float v = acc[mi][ni][j] + bs[ni];
        if constexpr (EPI == 0) {
          ((u16*)Cout)[(size_t)rr * 2048 + c] = f2bf(v);   // Q,K -> [T][2048]
        } else if constexpr (EPI == 1) {
          const size_t idx = (size_t)rr * N + c;
          ((u16*)Cout)[idx] = f2bf(v + res[idx]);          // bf16 x1
        } else if constexpr (EPI == 2) {
          const size_t idx = (size_t)rr * N + c;
          ((u16*)Cout)[idx] = f2bf(gelu_tanh(v));
        } else {                                           // EPI == 3
          const size_t idx = (size_t)rr * N + c;
          ((float*)Cout)[idx] = v + bf2f((short)((const u16*)res)[idx]);
        }
      }
    }
  }
}

// ---------------------------------------------------------------------------
// Flash attention (causal), swapped-QK + transposed-PV; paired k-tiles,
// 6-tile K/V ring (round-16 version, passing).
// ---------------------------------------------------------------------------
__global__ __launch_bounds__(512) void attn_kernel(const u16* __restrict__ qk,
    const u16* __restrict__ vt, u16* __restrict__ obuf) {
  __shared__ __align__(16) u16 ldsK[6][64 * 64];
  __shared__ __align__(16) u16 ldsV[6][64 * 64];
  __shared__ __align__(16) u16 ldsP[8][2][16 * PST];
  const int tid = threadIdx.x, l = tid & 63, w = tid >> 6;
  const int lr = l & 15, lg = l >> 4;
  const int lid = (blockIdx.x & 7) * 32 + (blockIdx.x >> 3);   // 256 blocks
  const int bh = lid >> 2, bx = lid & 3;
  const int b = bh >> 4, h = bh & 15;
  const u16* qbase = qk + (size_t)b * SEQ * 2048 + h * 64;
  const u16* kbase = qk + (size_t)b * SEQ * 2048 + 1024 + h * 64;
  const u16* vbase = vt + (size_t)bh * 64 * SEQ;

  const int srow = tid >> 3;                     // 0..63
  const int scb  = ((tid & 7) * 16) ^ ((srow & 7) << 4);   // swizzled col bytes
  const int sel  = scb >> 1;                     // element offset in 64-col row

  auto stageKV = [&](int t) {
    const int bi = t % 6;
    gload16(kbase + (size_t)(t * 64 + srow) * 2048 + sel, &ldsK[bi][tid * 8]);
    gload16(vbase + (size_t)srow * SEQ + t * 64 + sel,    &ldsV[bi][tid * 8]);
  };

#pragma unroll
  for (int half = 0; half < 2; ++half) {
    const int qt = half ? (7 - bx) : bx;
    const int q0 = qt * 256 + w * 32;            // wave's first q row
    bf16x8 qf[2][2];
#pragma unroll
    for (int mi = 0; mi < 2; ++mi)
#pragma unroll
      for (int ks = 0; ks < 2; ++ks) {
        bf16x8 raw = *(const bf16x8*)(qbase +
            (size_t)(q0 + mi * 16 + lr) * 2048 + ks * 32 + lg * 8);
        bf16x8 sc8;
#pragma unroll
        for (int i = 0; i < 8; ++i) sc8[i] = (short)f2bf(bf2f(raw[i]) * 0.125f);
        qf[mi][ks] = sc8;
      }

    f32x4 o[2][4];
#pragma unroll
    for (int mi = 0; mi < 2; ++mi)
#pragma unroll
      for (int nd = 0; nd < 4; ++nd) o[mi][nd] = f32x4{0.f, 0.f, 0.f, 0.f};
    float m_[2] = {-1e30f, -1e30f}, ls[2] = {0.f, 0.f};

    const int nt = 4 * qt + 4;                   // always even
    const int nip = nt >> 1;                     // paired iterations
    const int qmaxw = q0 + 31;

    stageKV(0); stageKV(1);                      // prologue (4 loads)

    for (int jt = 0; jt < nip; ++jt) {
      const int k0t = 2 * jt;
      if (jt + 1 < nip) {
        stageKV(k0t + 2); stageKV(k0t + 3);      // into slots read 2 bars ago
        asm volatile("s_waitcnt vmcnt(4)" ::: "memory");   // k0t,k0t+1 landed
      } else {
        asm volatile("s_waitcnt vmcnt(0)" ::: "memory");
      }
      __builtin_amdgcn_s_barrier();              // publish pair (all waves)
      __builtin_amdgcn_sched_barrier(0);

#pragma unroll
      for (int sub = 0; sub < 2; ++sub) {
        const int kt = k0t + sub;
        const u16* bK = &ldsK[kt % 6][0];
        const u16* bV = &ldsV[kt % 6][0];

        if (kt * 64 <= qmaxw) {        // wave has live rows in this k-tile
          // ---- S^T = K . Q^T  (col = q = lr, row = key) ----
          f32x4 sc[2][4];
#pragma unroll
          for (int mi = 0; mi < 2; ++mi)
#pragma unroll
            for (int ni = 0; ni < 4; ++ni) sc[mi][ni] = f32x4{0.f, 0.f, 0.f, 0.f};
#pragma unroll
          for (int ks = 0; ks < 2; ++ks)
#pragma unroll
            for (int ni = 0; ni < 4; ++ni) {
              const int r2 = ni * 16 + lr;
              const int cb = (r2 << 7) + ((ks * 64 + lg * 16) ^ ((r2 & 7) << 4));
              bf16x8 kf = *(const bf16x8*)&bK[cb >> 1];
              sc[0][ni] = __builtin_amdgcn_mfma_f32_16x16x32_bf16(kf, qf[0][ks], sc[0][ni], 0, 0, 0);
              sc[1][ni] = __builtin_amdgcn_mfma_f32_16x16x32_bf16(kf, qf[1][ks], sc[1][ni], 0, 0, 0);
            }

          // ---- causal mask ----
          if (kt * 64 + 63 > q0) {
#pragma unroll
            for (int mi = 0; mi < 2; ++mi) {
              const int qa = q0 + mi * 16 + lr;
#pragma unroll
              for (int ni = 0; ni < 4; ++ni)
#pragma unroll
                for (int j = 0; j < 4; ++j) {
                  const int ka = kt * 64 + ni * 16 + lg * 4 + j;
                  if (ka > qa) sc[mi][ni][j] = -1e30f;
                }
            }
          }

          // ---- online softmax (lane-local row q = lr; T13 defer-max) ----
#pragma unroll
          for (int mi = 0; mi < 2; ++mi) {
            float mx = sc[mi][0][0];
#pragma unroll
            for (int ni = 0; ni < 4; ++ni)
#pragma unroll
              for (int j = 0; j < 4; ++j) mx = fmaxf(mx, sc[mi][ni][j]);
            mx = fmaxf(mx, __shfl_xor(mx, 16, 64));
            mx = fmaxf(mx, __shfl_xor(mx, 32, 64));
            if (!__all(mx <= m_[mi] + 8.0f)) {   // rescale only when needed
              const float newm = fmaxf(m_[mi], mx);
              const float alpha = __expf(m_[mi] - newm);
              m_[mi] = newm;
              ls[mi] *= alpha;
#pragma unroll
              for (int nd = 0; nd < 4; ++nd) {
                o[mi][nd][0] *= alpha; o[mi][nd][1] *= alpha;
                o[mi][nd][2] *= alpha; o[mi][nd][3] *= alpha;
              }
            }
            float ps = 0.f;
#pragma unroll
            for (int ni = 0; ni < 4; ++ni) {
              float p0 = __expf(sc[mi][ni][0] - m_[mi]);
              float p1 = __expf(sc[mi][ni][1] - m_[mi]);
              float p2 = __expf(sc[mi][ni][2] - m_[mi]);
              float p3 = __expf(sc[mi][ni][3] - m_[mi]);
              ps += (p0 + p1) + (p2 + p3);
              u32 w0 = pk2(p0, p1), w1 = pk2(p2, p3);
              *(uint2*)&ldsP[w][mi][lr * PST + ni * 16 + lg * 4] = make_uint2(w0, w1);
            }
            ps += __shfl_xor(ps, 16, 64);        // row total (across lg)
            ps += __shfl_xor(ps, 32, 64);
            ls[mi] += ps;
          }

          // ---- O^T += V^T . P  (row = d, col = q = lr) ----
#pragma unroll
          for (int ks = 0; ks < 2; ++ks) {
            bf16x8 pf0 = *(const bf16x8*)&ldsP[w][0][lr * PST + ks * 32 + lg * 8];
            bf16x8 pf1 = *(const bf16x8*)&ldsP[w][1][lr * PST + ks * 32 + lg * 8];
#pragma unroll
            for (int nd = 0; nd < 4; ++nd) {
              const int r2 = nd * 16 + lr;
              const int cb = (r2 << 7) + ((ks * 64 + lg * 16) ^ ((r2 & 7) << 4));
              bf16x8 vf = *(const bf16x8*)&bV[cb >> 1];
              o[0][nd] = __builtin_amdgcn_mfma_f32_16x16x32_bf16(vf, pf0, o[0][nd], 0, 0, 0);
              o[1][nd] = __builtin_amdgcn_mfma_f32_16x16x32_bf16(vf, pf1, o[1][nd], 0, 0, 0);
            }
          }
        }
      }
    }
    __builtin_amdgcn_s_barrier();     // protect ring before next half restages

    // ---- epilogue: O^T / l ; q = lr (lane-local), d = nd*16 + lg*4 + j ----
#pragma unroll
    for (int mi = 0; mi < 2; ++mi) {
      const float inv = 1.0f / ls[mi];
      const int qrow = q0 + mi * 16 + lr;
      u16* op = obuf + (size_t)(b * SEQ + qrow) * DM + h * 64 + lg * 4;
#pragma unroll
      for (int nd = 0; nd < 4; ++nd) {
        ushort4 pk = { f2bf(o[mi][nd][0] * inv), f2bf(o[mi][nd][1] * inv),
                       f2bf(o[mi][nd][2] * inv), f2bf(o[mi][nd][3] * inv) };
        *(ushort4*)(op + nd * 16) = pk;
      }
    }
  }
}

// ---------------------------------------------------------------------------
extern "C" void kernel_launch(void* const* d_in, const int* in_sizes, int n_in,
                              void* d_out, int out_size, void* d_ws, size_t ws_size,
                              hipStream_t stream) {
  const float* x   = (const float*)d_in[0];
  const float* Wq  = (const float*)d_in[1];
  const float* bq  = (const float*)d_in[2];
  const float* Wk  = (const float*)d_in[3];
  const float* bk  = (const float*)d_in[4];
  const float* Wv  = (const float*)d_in[5];
  const float* bv  = (const float*)d_in[6];
  const float* Wo  = (const float*)d_in[7];
  const float* bo  = (const float*)d_in[8];
  const float* g1  = (const float*)d_in[9];
  const float* be1 = (const float*)d_in[10];
  const float* g2  = (const float*)d_in[11];
  const float* be2 = (const float*)d_in[12];
  const float* W1  = (const float*)d_in[13];
  const float* bf1 = (const float*)d_in[14];
  const float* W2  = (const float*)d_in[15];
  const float* bf2 = (const float*)d_in[16];
  float* out = (float*)d_out;   // final f32 output (fully rewritten by FFN2)

  char* ws = (char*)d_ws;
  size_t off = 0;
  auto alloc = [&](size_t bytes) {
    char* p = ws + off;
    off += (bytes + 255) & ~(size_t)255;
    return p;
  };
  u16* xnB = (u16*)alloc((size_t)T_TOK * DM * 2);     // 16 MB (xn, later xn2)
  // Region D (64 MB): MHA = qkB(32) | VTg(16) | oB(16); FFN = H(64)
  u16* D    = (u16*)alloc((size_t)T_TOK * 4096 * 2);  // 64 MB
  u16* qkB  = D;                                      // [T][2048]
  u16* VTg  = D + (size_t)T_TOK * 2048;               // [B*H][64][2048]
  u16* oB   = D + (size_t)T_TOK * 3072;               // [T][1024] attn out
  u16* HB   = D;                                      // [T][4096] (FFN phase)
  u16*   WqkvB = (u16*)alloc((size_t)3072 * 1024 * 2);
  u16*   WoB   = (u16*)alloc((size_t)1024 * 1024 * 2);
  u16*   W1B   = (u16*)alloc((size_t)4096 * 1024 * 2);
  u16*   W2B   = (u16*)alloc((size_t)1024 * 4096 * 2);
  u16*   x1B   = (u16*)alloc((size_t)T_TOK * DM * 2); // 16 MB bf16 residual
  float* bqkv  = (float*)alloc(3072 * 4);

  // fused prep: LN1 + weight casts + bias concat (one launch)
  prep_kernel<<<10252, 256, 0, stream>>>(x, g1, be1, xnB,
                                         Wq, Wk, Wv, Wo, W1, W2,
                                         WqkvB, WoB, W1B, W2B,
                                         bq, bk, bv, bqkv);

  // MHA sublayer (QKV writes Q,K -> qkB and transposed V -> VTg directly)
  gemm8p<0, 128><<<768, 512, 0, stream>>>(xnB, WqkvB, bqkv, nullptr,
                                          qkB, VTg, T_TOK, 3072, 1024, 12);
  attn_kernel<<<256, 512, 0, stream>>>(qkB, VTg, oB);
  gemm8p<1, 128><<<256, 512, 0, stream>>>(oB, WoB, bo, x,
                                          x1B, nullptr, T_TOK, 1024, 1024, 4);

  // FFN sublayer (bf16 residual path)
  ln_kernel_b<<<T_TOK, 256, 0, stream>>>(x1B, g2, be2, xnB);
  gemm8p<2, 256><<<512, 512, 0, stream>>>(xnB, W1B, bf1, nullptr,
                                          HB, nullptr, T_TOK, 4096, 1024, 16);
  gemm8p<3, 128><<<256, 512, 0, stream>>>(HB, W2B, bf2, (const float*)x1B,
                                          out, nullptr, T_TOK, 1024, 4096, 4);
}

// Round 18
// 343.845 us; speedup vs baseline: 1.0673x; 1.0024x over previous
//
#include <hip/hip_runtime.h>
#include <math.h>

// ---------------------------------------------------------------------------
// Transformer encoder block, MI355X gfx950.  Round 17: bf16 residual path.
//   - x1 (post-attn residual) stored as bf16 (x1B, 16 MB) instead of f32
//     d_out: Wo write, LN2 read, FFN2 residual read all halve (-48 MB).
//     EPI=1 -> bf16 x1 out; new EPI=3 -> f32 final out with bf16 residual;
//     ln_kernel_b = bf16-input LayerNorm.
//   - GEMM K-loop / attn / prep: round-16 configuration (plateau-verified).
// ---------------------------------------------------------------------------

typedef unsigned short u16;
typedef unsigned int u32;
typedef __attribute__((ext_vector_type(8))) short bf16x8;   // 8 bf16 = 4 VGPRs
typedef __attribute__((ext_vector_type(4))) float f32x4;

#define T_TOK 8192      // 4 * 2048 tokens
#define DM    1024      // model dim
#define SEQ   2048
#define PST   88        // attn ldsP row stride (u16)
#define TST   136       // V-transpose LDS row stride (u16)

__device__ __forceinline__ u16 f2bf(float f) {
  union { float f; unsigned int u; } c; c.f = f;
  unsigned int u = c.u + 0x7fffu + ((c.u >> 16) & 1u);   // RNE
  return (u16)(u >> 16);
}

__device__ __forceinline__ u32 pk2(float a, float b) {
  return (u32)f2bf(a) | ((u32)f2bf(b) << 16);
}

__device__ __forceinline__ float bf2f(short s) {
  union { float f; unsigned int u; } c; c.u = ((u32)(u16)s) << 16;
  return c.f;
}

__device__ __forceinline__ void gload16(const void* gp, void* lp) {
  __builtin_amdgcn_global_load_lds(
      (const __attribute__((address_space(1))) void*)gp,
      (__attribute__((address_space(3))) void*)lp, 16, 0, 0);
}

__device__ __forceinline__ float gelu_tanh(float v) {
  float u = 0.7978845608f * (v + 0.044715f * v * v * v);
  return v / (1.0f + __expf(-2.0f * u));
}

// ---------------------------------------------------------------------------
// prep_kernel: blocks [0,8192) = LN1 rows; [8192,10240) = weight casts;
//              [10240,10252) = qkv bias concat.
// ---------------------------------------------------------------------------
__global__ __launch_bounds__(256) void prep_kernel(
    const float* __restrict__ x, const float* __restrict__ g,
    const float* __restrict__ b, u16* __restrict__ xnB,
    const float* __restrict__ Wq, const float* __restrict__ Wk,
    const float* __restrict__ Wv, const float* __restrict__ Wo,
    const float* __restrict__ W1, const float* __restrict__ W2,
    u16* __restrict__ WqkvB, u16* __restrict__ WoB,
    u16* __restrict__ W1B, u16* __restrict__ W2B,
    const float* __restrict__ bq, const float* __restrict__ bk,
    const float* __restrict__ bv, float* __restrict__ bqkv) {
  __shared__ float red[4];
  const int bid = blockIdx.x, tid = threadIdx.x;
  if (bid < 8192) {
    const int l = tid & 63, w = tid >> 6;
    const size_t row = bid;
    float4 v = reinterpret_cast<const float4*>(x + row * DM)[tid];
    float s = v.x + v.y + v.z + v.w;
#pragma unroll
    for (int off = 1; off < 64; off <<= 1) s += __shfl_xor(s, off, 64);
    if (l == 0) red[w] = s;
    __syncthreads();
    float mu = (red[0] + red[1] + red[2] + red[3]) * (1.0f / 1024.0f);
    float dx = v.x - mu, dy = v.y - mu, dz = v.z - mu, dw = v.w - mu;
    float ss = dx * dx + dy * dy + dz * dz + dw * dw;
#pragma unroll
    for (int off = 1; off < 64; off <<= 1) ss += __shfl_xor(ss, off, 64);
    __syncthreads();
    if (l == 0) red[w] = ss;
    __syncthreads();
    float var = (red[0] + red[1] + red[2] + red[3]) * (1.0f / 1023.0f);
    float inv = 1.0f / (sqrtf(var) + 1e-8f);
    const int c = tid * 4;
    u16* o = xnB + row * DM + c;
    o[0] = f2bf(dx * inv * g[c + 0] + b[c + 0]);
    o[1] = f2bf(dy * inv * g[c + 1] + b[c + 1]);
    o[2] = f2bf(dz * inv * g[c + 2] + b[c + 2]);
    o[3] = f2bf(dw * inv * g[c + 3] + b[c + 3]);
  } else if (bid < 10240) {
    for (int i = (bid - 8192) * 256 + tid; i < 3145728; i += 2048 * 256) {
      const float* s; u16* d; int j;
      if (i < 262144)       { s = Wq; d = WqkvB;           j = i; }
      else if (i < 524288)  { s = Wk; d = WqkvB + 1048576; j = i - 262144; }
      else if (i < 786432)  { s = Wv; d = WqkvB + 2097152; j = i - 524288; }
      else if (i < 1048576) { s = Wo; d = WoB;             j = i - 786432; }
      else if (i < 2097152) { s = W1; d = W1B;             j = i - 1048576; }
      else                  { s = W2; d = W2B;             j = i - 2097152; }
      float4 v = reinterpret_cast<const float4*>(s)[j];
      ushort4 o = { f2bf(v.x), f2bf(v.y), f2bf(v.z), f2bf(v.w) };
      reinterpret_cast<ushort4*>(d)[j] = o;
    }
  } else {
    int i = (bid - 10240) * 256 + tid;           // 0..3071
    float val = (i < 1024) ? bq[i] : (i < 2048) ? bk[i - 1024] : bv[i - 2048];
    bqkv[i] = val;
  }
}

// ---------------------------------------------------------------------------
// LayerNorm, bf16 input (used for LN2 on x1B)
// ---------------------------------------------------------------------------
__global__ __launch_bounds__(256) void ln_kernel_b(const u16* __restrict__ x,
    const float* __restrict__ g, const float* __restrict__ b, u16* __restrict__ out) {
  __shared__ float red[4];
  const int tid = threadIdx.x, l = tid & 63, w = tid >> 6;
  const size_t row = blockIdx.x;
  ushort4 raw = reinterpret_cast<const ushort4*>(x + row * DM)[tid];
  float vx = bf2f((short)raw.x), vy = bf2f((short)raw.y);
  float vz = bf2f((short)raw.z), vw = bf2f((short)raw.w);
  float s = vx + vy + vz + vw;
#pragma unroll
  for (int off = 1; off < 64; off <<= 1) s += __shfl_xor(s, off, 64);
  if (l == 0) red[w] = s;
  __syncthreads();
  float mu = (red[0] + red[1] + red[2] + red[3]) * (1.0f / 1024.0f);
  float dx = vx - mu, dy = vy - mu, dz = vz - mu, dw = vw - mu;
  float ss = dx * dx + dy * dy + dz * dz + dw * dw;
#pragma unroll
  for (int off = 1; off < 64; off <<= 1) ss += __shfl_xor(ss, off, 64);
  __syncthreads();
  if (l == 0) red[w] = ss;
  __syncthreads();
  float var = (red[0] + red[1] + red[2] + red[3]) * (1.0f / 1023.0f);
  float inv = 1.0f / (sqrtf(var) + 1e-8f);
  const int c = tid * 4;
  u16* o = out + row * DM + c;
  o[0] = f2bf(dx * inv * g[c + 0] + b[c + 0]);
  o[1] = f2bf(dy * inv * g[c + 1] + b[c + 1]);
  o[2] = f2bf(dz * inv * g[c + 2] + b[c + 2]);
  o[3] = f2bf(dw * inv * g[c + 3] + b[c + 3]);
}

// ---------------------------------------------------------------------------
// gemm8p<EPI, BM>: C[M,N] = A[M,K] @ Bw[N,K]^T + bias (+res) (+gelu)
// m201-style 8-phase schedule, BK=64, 2 K-tiles per loop iteration.
// EPI 0: QKV (Q,K -> Cout [T][2048]; V tile -> in-LDS transpose -> aux VT).
// EPI 1: bf16 out (bias + f32 res)      [Wo -> x1B]
// EPI 2: bf16 out (bias + gelu)         [FFN1 -> H]
// EPI 3: f32 out (bias + bf16 res)      [FFN2 -> d_out]
// ---------------------------------------------------------------------------
template <int EPI, int BM>
__global__ __launch_bounds__(512) void gemm8p(const u16* __restrict__ A,
    const u16* __restrict__ Bw, const float* __restrict__ bias,
    const float* res, void* Cout, void* aux, int M, int N, int K, int gx) {
  constexpr int MI  = BM / 32;                 // acc rows (8 or 4)
  constexpr int AMI = MI / 2;                  // A frags per phase (4 or 2)
  constexpr int VC  = (BM == 256) ? 6 : 5;     // counted vmcnt
  __shared__ __align__(16) u16 shm[BM * 128 + 256 * 128];
  const int tid = threadIdx.x;
  const int l = tid & 63;
  const int w = tid >> 6;
  const int wm = w >> 2, wn = w & 3;
  const int lr = l & 15, lg = l >> 4;

  // ---- XCD supertile remap (T1) ----
  const int nb = gridDim.x;
  const int q = nb >> 3, r = nb & 7;
  const int xcd = blockIdx.x & 7, jj = blockIdx.x >> 3;
  const int lid = (xcd < r ? xcd * (q + 1) : r * (q + 1) + (xcd - r) * q) + jj;
  const int stid = lid >> 5, pos = lid & 31;
  const int nstx = gx >> 2;
  const int stx = stid % nstx, sty = stid / nstx;
  const int bx = stx * 4 + (pos & 3), by = sty * 8 + (pos >> 2);
  const int m0 = by * BM, n0 = bx * 256;

  // ---- staging source (pre-swizzled): D = tid*16, L = D ^ ((D>>7)&3)<<4 ----
  const int Dl = tid * 16;
  const int Ls = Dl ^ (((Dl >> 7) & 3) << 4);
  const int srow = Ls >> 6;            // 0..127
  const int scol = (Ls & 63) >> 1;     // element col 0..31 (8-aligned)
  const u16* aS0 = A  + (size_t)(m0 + srow) * K + scol;
  const u16* aS1 = aS0 + (size_t)128 * K;          // BM==256 only
  const u16* bS0 = Bw + (size_t)(n0 + srow) * K + scol;
  const u16* bS1 = bS0 + (size_t)128 * K;

  // ---- ds_read bases (swizzled; XOR term constant per lane) ----
  const int sx = ((lr >> 1) & 3) << 4;
  const int aBase = (wm * (BM / 2) + lr) * 64 + ((lg * 16) ^ sx);  // bytes
  const int bBase = (wn * 64 + lr) * 64 + ((lg * 16) ^ sx);

  f32x4 acc[MI][4];
#pragma unroll
  for (int i = 0; i < MI; ++i)
#pragma unroll
    for (int j = 0; j < 4; ++j) acc[i][j] = f32x4{0.f, 0.f, 0.f, 0.f};
  bf16x8 bv[2][4];

  const int NT = K >> 6;               // K-tiles of 64
  const int NI = NT >> 1;              // loop iterations (2 tiles each)

  auto stA = [&](int d, int ks, int tile) {
    u16* dst = shm + (d * 2 + ks) * (BM * 32) + tid * 8;
    const int ko = tile * 64 + ks * 32;
    gload16(aS0 + ko, dst);
    if constexpr (BM == 256) gload16(aS1 + ko, dst + 4096);
  };
  auto stB = [&](int d, int ks, int tile) {
    u16* dst = shm + BM * 128 + (d * 2 + ks) * (256 * 32) + tid * 8;
    const int ko = tile * 64 + ks * 32;
    gload16(bS0 + ko, dst);
    gload16(bS1 + ko, dst + 4096);
  };

  // ---- prologue: tile0 -> d0 (4 halves), tile1 -> d1 (B0,B1,A-ks0) ----
  stB(0, 0, 0); stB(0, 1, 0); stA(0, 0, 0); stA(0, 1, 0);
  stB(1, 0, 1); stB(1, 1, 1); stA(1, 0, 1);
  asm volatile("s_waitcnt vmcnt(%0)" :: "i"(VC) : "memory");
  __builtin_amdgcn_sched_barrier(0);
  __builtin_amdgcn_s_barrier();

#define PHASE(DBUF, KS, MH, READB, STAGE, ENDV)                               \
  {                                                                           \
    const char* abuf = (const char*)(shm + ((DBUF) * 2 + (KS)) * (BM * 32));  \
    const char* bbuf =                                                        \
        (const char*)(shm + BM * 128 + ((DBUF) * 2 + (KS)) * (256 * 32));     \
    bf16x8 av[AMI];                                                           \
    _Pragma("unroll")                                                         \
    for (int i = 0; i < AMI; ++i)                                             \
      av[i] = *(const bf16x8*)(abuf + aBase + ((MH) * AMI + i) * 1024);       \
    if (READB) {                                                              \
      _Pragma("unroll")                                                       \
      for (int ni = 0; ni < 4; ++ni)                                          \
        bv[KS][ni] = *(const bf16x8*)(bbuf + bBase + ni * 1024);              \
    }                                                                         \
    STAGE;                                                                    \
    __builtin_amdgcn_s_barrier();                                             \
    asm volatile("s_waitcnt lgkmcnt(0)" ::: "memory");                        \
    __builtin_amdgcn_sched_barrier(0);                                        \
    __builtin_amdgcn_s_setprio(1);                                            \
    _Pragma("unroll")                                                         \
    for (int i = 0; i < AMI; ++i)                                             \
      _Pragma("unroll")                                                       \
      for (int ni = 0; ni < 4; ++ni)                                          \
        acc[(MH) * AMI + i][ni] = __builtin_amdgcn_mfma_f32_16x16x32_bf16(    \
            av[i], bv[KS][ni], acc[(MH) * AMI + i][ni], 0, 0, 0);             \
    __builtin_amdgcn_s_setprio(0);                                            \
    ENDV;                                                                     \
    __builtin_amdgcn_s_barrier();                                             \
  }

#define ENDV_CNT                                                              \
  {                                                                           \
    if (t + 1 < NI) {                                                         \
      asm volatile("s_waitcnt vmcnt(%0)" :: "i"(VC) : "memory");              \
    } else {                                                                  \
      asm volatile("s_waitcnt vmcnt(0)" ::: "memory");                        \
    }                                                                         \
    __builtin_amdgcn_sched_barrier(0);                                        \
  }

  for (int t = 0; t < NI; ++t) {
    const int t2 = 2 * t;
    const bool s0 = (t2 + 2 < NT);     // stage tile 2t+2 (d0)
    const bool s1 = (t2 + 3 < NT);     // stage tile 2t+3 (d1)
    // p0..p3: compute tile 2t (d0); p4..p7: tile 2t+1 (d1)
    PHASE(0, 0, 0, 1, { stA(1, 1, t2 + 1); }, {});                 // p0
    PHASE(0, 1, 0, 1, { if (s0) stB(0, 0, t2 + 2); }, {});         // p1
    PHASE(0, 0, 1, 0, { if (s0) stB(0, 1, t2 + 2); }, {});         // p2
    PHASE(0, 1, 1, 0, { if (s0) stA(0, 0, t2 + 2); }, ENDV_CNT);   // p3
    PHASE(1, 0, 0, 1, { if (s0) stA(0, 1, t2 + 2); }, {});         // p4
    PHASE(1, 1, 0, 1, { if (s1) stB(1, 0, t2 + 3); }, {});         // p5
    PHASE(1, 0, 1, 0, { if (s1) stB(1, 1, t2 + 3); }, {});         // p6
    PHASE(1, 1, 1, 0, { if (s1) stA(1, 0, t2 + 3); }, ENDV_CNT);   // p7
  }
#undef PHASE
#undef ENDV_CNT

  // ---- epilogue ----
  float bs[4];
#pragma unroll
  for (int ni = 0; ni < 4; ++ni) bs[ni] = bias[n0 + wn * 64 + ni * 16 + lr];

  if constexpr (EPI == 0) {
    if (n0 >= 2048) {
      // ---- V tile: in-LDS transpose, coalesced VT write ----
      u16* ldsT = shm;                          // 256*TST u16 fits
#pragma unroll
      for (int mi = 0; mi < MI; ++mi)
#pragma unroll
        for (int ni = 0; ni < 4; ++ni) {
          const int c = wn * 64 + ni * 16 + lr;
          const int r0 = wm * (BM / 2) + mi * 16 + lg * 4;
          ushort4 pk = { f2bf(acc[mi][ni][0] + bs[ni]),
                         f2bf(acc[mi][ni][1] + bs[ni]),
                         f2bf(acc[mi][ni][2] + bs[ni]),
                         f2bf(acc[mi][ni][3] + bs[ni]) };
          *(ushort4*)&ldsT[c * TST + r0] = pk;
        }
      __syncthreads();
      const int b0 = m0 >> 11, s0b = m0 & 2047;
      const int cc = tid >> 1, hf = tid & 1;
      const int hd = (n0 - 2048) + cc, hh = hd >> 6, dd = hd & 63;
      u16* dst = (u16*)aux +
                 (((size_t)(b0 * 16 + hh) * 64 + dd) << 11) + s0b + hf * 64;
      const u16* srcT = &ldsT[cc * TST + hf * 64];
#pragma unroll
      for (int i2 = 0; i2 < 8; ++i2)
        *(bf16x8*)(dst + i2 * 8) = *(const bf16x8*)(srcT + i2 * 8);
      return;
    }
  }

#pragma unroll
  for (int mi = 0; mi < MI; ++mi) {
#pragma unroll
    for (int j = 0; j < 4; ++j) {
      const int rr = m0 + wm * (BM / 2) + mi * 16 + lg * 4 + j;
#pragma unroll
      for (int ni = 0; ni < 4; ++ni) {
        const int c = n0 + wn * 64 + ni * 16 + lr;
        float v = acc[mi][ni][j] + bs[ni];
        if constexpr (EPI == 0) {
          ((u16*)Cout)[(size_t)rr * 2048 + c] = f2bf(v);   // Q,K -> [T][2048]
        } else if constexpr (EPI == 1) {
          const size_t idx = (size_t)rr * N + c;
          ((u16*)Cout)[idx] = f2bf(v + res[idx]);          // bf16 x1
        } else if constexpr (EPI == 2) {
          const size_t idx = (size_t)rr * N + c;
          ((u16*)Cout)[idx] = f2bf(gelu_tanh(v));
        } else {                                           // EPI == 3
          const size_t idx = (size_t)rr * N + c;
          ((float*)Cout)[idx] = v + bf2f((short)((const u16*)res)[idx]);
        }
      }
    }
  }
}

// ---------------------------------------------------------------------------
// Flash attention (causal), swapped-QK + transposed-PV; paired k-tiles,
// 6-tile K/V ring (round-16 version, passing).
// ---------------------------------------------------------------------------
__global__ __launch_bounds__(512) void attn_kernel(const u16* __restrict__ qk,
    const u16* __restrict__ vt, u16* __restrict__ obuf) {
  __shared__ __align__(16) u16 ldsK[6][64 * 64];
  __shared__ __align__(16) u16 ldsV[6][64 * 64];
  __shared__ __align__(16) u16 ldsP[8][2][16 * PST];
  const int tid = threadIdx.x, l = tid & 63, w = tid >> 6;
  const int lr = l & 15, lg = l >> 4;
  const int lid = (blockIdx.x & 7) * 32 + (blockIdx.x >> 3);   // 256 blocks
  const int bh = lid >> 2, bx = lid & 3;
  const int b = bh >> 4, h = bh & 15;
  const u16* qbase = qk + (size_t)b * SEQ * 2048 + h * 64;
  const u16* kbase = qk + (size_t)b * SEQ * 2048 + 1024 + h * 64;
  const u16* vbase = vt + (size_t)bh * 64 * SEQ;

  const int srow = tid >> 3;                     // 0..63
  const int scb  = ((tid & 7) * 16) ^ ((srow & 7) << 4);   // swizzled col bytes
  const int sel  = scb >> 1;                     // element offset in 64-col row

  auto stageKV = [&](int t) {
    const int bi = t % 6;
    gload16(kbase + (size_t)(t * 64 + srow) * 2048 + sel, &ldsK[bi][tid * 8]);
    gload16(vbase + (size_t)srow * SEQ + t * 64 + sel,    &ldsV[bi][tid * 8]);
  };

#pragma unroll
  for (int half = 0; half < 2; ++half) {
    const int qt = half ? (7 - bx) : bx;
    const int q0 = qt * 256 + w * 32;            // wave's first q row
    bf16x8 qf[2][2];
#pragma unroll
    for (int mi = 0; mi < 2; ++mi)
#pragma unroll
      for (int ks = 0; ks < 2; ++ks) {
        bf16x8 raw = *(const bf16x8*)(qbase +
            (size_t)(q0 + mi * 16 + lr) * 2048 + ks * 32 + lg * 8);
        bf16x8 sc8;
#pragma unroll
        for (int i = 0; i < 8; ++i) sc8[i] = (short)f2bf(bf2f(raw[i]) * 0.125f);
        qf[mi][ks] = sc8;
      }

    f32x4 o[2][4];
#pragma unroll
    for (int mi = 0; mi < 2; ++mi)
#pragma unroll
      for (int nd = 0; nd < 4; ++nd) o[mi][nd] = f32x4{0.f, 0.f, 0.f, 0.f};
    float m_[2] = {-1e30f, -1e30f}, ls[2] = {0.f, 0.f};

    const int nt = 4 * qt + 4;                   // always even
    const int nip = nt >> 1;                     // paired iterations
    const int qmaxw = q0 + 31;

    stageKV(0); stageKV(1);                      // prologue (4 loads)

    for (int jt = 0; jt < nip; ++jt) {
      const int k0t = 2 * jt;
      if (jt + 1 < nip) {
        stageKV(k0t + 2); stageKV(k0t + 3);      // into slots read 2 bars ago
        asm volatile("s_waitcnt vmcnt(4)" ::: "memory");   // k0t,k0t+1 landed
      } else {
        asm volatile("s_waitcnt vmcnt(0)" ::: "memory");
      }
      __builtin_amdgcn_s_barrier();              // publish pair (all waves)
      __builtin_amdgcn_sched_barrier(0);

#pragma unroll
      for (int sub = 0; sub < 2; ++sub) {
        const int kt = k0t + sub;
        const u16* bK = &ldsK[kt % 6][0];
        const u16* bV = &ldsV[kt % 6][0];

        if (kt * 64 <= qmaxw) {        // wave has live rows in this k-tile
          // ---- S^T = K . Q^T  (col = q = lr, row = key) ----
          f32x4 sc[2][4];
#pragma unroll
          for (int mi = 0; mi < 2; ++mi)
#pragma unroll
            for (int ni = 0; ni < 4; ++ni) sc[mi][ni] = f32x4{0.f, 0.f, 0.f, 0.f};
#pragma unroll
          for (int ks = 0; ks < 2; ++ks)
#pragma unroll
            for (int ni = 0; ni < 4; ++ni) {
              const int r2 = ni * 16 + lr;
              const int cb = (r2 << 7) + ((ks * 64 + lg * 16) ^ ((r2 & 7) << 4));
              bf16x8 kf = *(const bf16x8*)&bK[cb >> 1];
              sc[0][ni] = __builtin_amdgcn_mfma_f32_16x16x32_bf16(kf, qf[0][ks], sc[0][ni], 0, 0, 0);
              sc[1][ni] = __builtin_amdgcn_mfma_f32_16x16x32_bf16(kf, qf[1][ks], sc[1][ni], 0, 0, 0);
            }

          // ---- causal mask ----
          if (kt * 64 + 63 > q0) {
#pragma unroll
            for (int mi = 0; mi < 2; ++mi) {
              const int qa = q0 + mi * 16 + lr;
#pragma unroll
              for (int ni = 0; ni < 4; ++ni)
#pragma unroll
                for (int j = 0; j < 4; ++j) {
                  const int ka = kt * 64 + ni * 16 + lg * 4 + j;
                  if (ka > qa) sc[mi][ni][j] = -1e30f;
                }
            }
          }

          // ---- online softmax (lane-local row q = lr; T13 defer-max) ----
#pragma unroll
          for (int mi = 0; mi < 2; ++mi) {
            float mx = sc[mi][0][0];
#pragma unroll
            for (int ni = 0; ni < 4; ++ni)
#pragma unroll
              for (int j = 0; j < 4; ++j) mx = fmaxf(mx, sc[mi][ni][j]);
            mx = fmaxf(mx, __shfl_xor(mx, 16, 64));
            mx = fmaxf(mx, __shfl_xor(mx, 32, 64));
            if (!__all(mx <= m_[mi] + 8.0f)) {   // rescale only when needed
              const float newm = fmaxf(m_[mi], mx);
              const float alpha = __expf(m_[mi] - newm);
              m_[mi] = newm;
              ls[mi] *= alpha;
#pragma unroll
              for (int nd = 0; nd < 4; ++nd) {
                o[mi][nd][0] *= alpha; o[mi][nd][1] *= alpha;
                o[mi][nd][2] *= alpha; o[mi][nd][3] *= alpha;
              }
            }
            float ps = 0.f;
#pragma unroll
            for (int ni = 0; ni < 4; ++ni) {
              float p0 = __expf(sc[mi][ni][0] - m_[mi]);
              float p1 = __expf(sc[mi][ni][1] - m_[mi]);
              float p2 = __expf(sc[mi][ni][2] - m_[mi]);
              float p3 = __expf(sc[mi][ni][3] - m_[mi]);
              ps += (p0 + p1) + (p2 + p3);
              u32 w0 = pk2(p0, p1), w1 = pk2(p2, p3);
              *(uint2*)&ldsP[w][mi][lr * PST + ni * 16 + lg * 4] = make_uint2(w0, w1);
            }
            ps += __shfl_xor(ps, 16, 64);        // row total (across lg)
            ps += __shfl_xor(ps, 32, 64);
            ls[mi] += ps;
          }

          // ---- O^T += V^T . P  (row = d, col = q = lr) ----
#pragma unroll
          for (int ks = 0; ks < 2; ++ks) {
            bf16x8 pf0 = *(const bf16x8*)&ldsP[w][0][lr * PST + ks * 32 + lg * 8];
            bf16x8 pf1 = *(const bf16x8*)&ldsP[w][1][lr * PST + ks * 32 + lg * 8];
#pragma unroll
            for (int nd = 0; nd < 4; ++nd) {
              const int r2 = nd * 16 + lr;
              const int cb = (r2 << 7) + ((ks * 64 + lg * 16) ^ ((r2 & 7) << 4));
              bf16x8 vf = *(const bf16x8*)&bV[cb >> 1];
              o[0][nd] = __builtin_amdgcn_mfma_f32_16x16x32_bf16(vf, pf0, o[0][nd], 0, 0, 0);
              o[1][nd] = __builtin_amdgcn_mfma_f32_16x16x32_bf16(vf, pf1, o[1][nd], 0, 0, 0);
            }
          }
        }
      }
    }
    __builtin_amdgcn_s_barrier();     // protect ring before next half restages

    // ---- epilogue: O^T / l ; q = lr (lane-local), d = nd*16 + lg*4 + j ----
#pragma unroll
    for (int mi = 0; mi < 2; ++mi) {
      const float inv = 1.0f / ls[mi];
      const int qrow = q0 + mi * 16 + lr;
      u16* op = obuf + (size_t)(b * SEQ + qrow) * DM + h * 64 + lg * 4;
#pragma unroll
      for (int nd = 0; nd < 4; ++nd) {
        ushort4 pk = { f2bf(o[mi][nd][0] * inv), f2bf(o[mi][nd][1] * inv),
                       f2bf(o[mi][nd][2] * inv), f2bf(o[mi][nd][3] * inv) };
        *(ushort4*)(op + nd * 16) = pk;
      }
    }
  }
}

// ---------------------------------------------------------------------------
extern "C" void kernel_launch(void* const* d_in, const int* in_sizes, int n_in,
                              void* d_out, int out_size, void* d_ws, size_t ws_size,
                              hipStream_t stream) {
  const float* x   = (const float*)d_in[0];
  const float* Wq  = (const float*)d_in[1];
  const float* bq  = (const float*)d_in[2];
  const float* Wk  = (const float*)d_in[3];
  const float* bk  = (const float*)d_in[4];
  const float* Wv  = (const float*)d_in[5];
  const float* bv  = (const float*)d_in[6];
  const float* Wo  = (const float*)d_in[7];
  const float* bo  = (const float*)d_in[8];
  const float* g1  = (const float*)d_in[9];
  const float* be1 = (const float*)d_in[10];
  const float* g2  = (const float*)d_in[11];
  const float* be2 = (const float*)d_in[12];
  const float* W1  = (const float*)d_in[13];
  const float* bf1 = (const float*)d_in[14];
  const float* W2  = (const float*)d_in[15];
  const float* bf2 = (const float*)d_in[16];
  float* out = (float*)d_out;   // final f32 output (fully rewritten by FFN2)

  char* ws = (char*)d_ws;
  size_t off = 0;
  auto alloc = [&](size_t bytes) {
    char* p = ws + off;
    off += (bytes + 255) & ~(size_t)255;
    return p;
  };
  u16* xnB = (u16*)alloc((size_t)T_TOK * DM * 2);     // 16 MB (xn, later xn2)
  // Region D (64 MB): MHA = qkB(32) | VTg(16) | oB(16); FFN = H(64)
  u16* D    = (u16*)alloc((size_t)T_TOK * 4096 * 2);  // 64 MB
  u16* qkB  = D;                                      // [T][2048]
  u16* VTg  = D + (size_t)T_TOK * 2048;               // [B*H][64][2048]
  u16* oB   = D + (size_t)T_TOK * 3072;               // [T][1024] attn out
  u16* HB   = D;                                      // [T][4096] (FFN phase)
  u16*   WqkvB = (u16*)alloc((size_t)3072 * 1024 * 2);
  u16*   WoB   = (u16*)alloc((size_t)1024 * 1024 * 2);
  u16*   W1B   = (u16*)alloc((size_t)4096 * 1024 * 2);
  u16*   W2B   = (u16*)alloc((size_t)1024 * 4096 * 2);
  u16*   x1B   = (u16*)alloc((size_t)T_TOK * DM * 2); // 16 MB bf16 residual
  float* bqkv  = (float*)alloc(3072 * 4);

  // fused prep: LN1 + weight casts + bias concat (one launch)
  prep_kernel<<<10252, 256, 0, stream>>>(x, g1, be1, xnB,
                                         Wq, Wk, Wv, Wo, W1, W2,
                                         WqkvB, WoB, W1B, W2B,
                                         bq, bk, bv, bqkv);

  // MHA sublayer (QKV writes Q,K -> qkB and transposed V -> VTg directly)
  gemm8p<0, 128><<<768, 512, 0, stream>>>(xnB, WqkvB, bqkv, nullptr,
                                          qkB, VTg, T_TOK, 3072, 1024, 12);
  attn_kernel<<<256, 512, 0, stream>>>(qkB, VTg, oB);
  gemm8p<1, 128><<<256, 512, 0, stream>>>(oB, WoB, bo, x,
                                          x1B, nullptr, T_TOK, 1024, 1024, 4);

  // FFN sublayer (bf16 residual path)
  ln_kernel_b<<<T_TOK, 256, 0, stream>>>(x1B, g2, be2, xnB);
  gemm8p<2, 256><<<512, 512, 0, stream>>>(xnB, W1B, bf1, nullptr,
                                          HB, nullptr, T_TOK, 4096, 1024, 16);
  gemm8p<3, 128><<<256, 512, 0, stream>>>(HB, W2B, bf2, (const float*)x1B,
                                          out, nullptr, T_TOK, 1024, 4096, 4);
}